// Round 2
// baseline (6612.613 us; speedup 1.0000x reference)
//
#include <hip/hip_runtime.h>

#define N_NODES 100000
#define N_HYPER 20000
#define N_EDGES 1600000
#define DD 128

// ---------------- degree + rsqrt ----------------
__global__ void k_deg(const int* __restrict__ src, const int* __restrict__ dst,
                      float* __restrict__ cn, float* __restrict__ ch) {
    int e = blockIdx.x * 256 + threadIdx.x;
    if (e < N_EDGES) {
        atomicAdd(&cn[src[e]], 1.0f);
        atomicAdd(&ch[dst[e]], 1.0f);
    }
}

__global__ void k_rsqrt(float* __restrict__ cn, float* __restrict__ ch) {
    int i = blockIdx.x * 256 + threadIdx.x;
    if (i < N_NODES) { float v = cn[i]; cn[i] = rsqrtf(v < 1.f ? 1.f : v); }
    if (i < N_HYPER) { float v = ch[i]; ch[i] = rsqrtf(v < 1.f ? 1.f : v); }
}

// ---------------- scatter 1: acc1[dst] += h[src] * cn[src] ----------------
// thread = (edge, 4-elem chunk); 32 chunks cover D=128
__global__ void k_scatter1(const float* __restrict__ h, const int* __restrict__ src,
                           const int* __restrict__ dst, const float* __restrict__ cn,
                           float* __restrict__ acc1) {
    int tt = blockIdx.x * 256 + threadIdx.x;
    int e = tt >> 5, c = tt & 31;
    if (e >= N_EDGES) return;
    int s = src[e], d = dst[e];
    float w = cn[s];
    const float4 v = *(const float4*)(h + s * DD + c * 4);
    float* p = acc1 + d * DD + c * 4;
    atomicAdd(p + 0, v.x * w);
    atomicAdd(p + 1, v.y * w);
    atomicAdd(p + 2, v.z * w);
    atomicAdd(p + 3, v.w * w);
}

// ------- GEMM1 (in-place): a := ((a*ch) @ W1 + b1) * ch  --------------------
__global__ __launch_bounds__(128) void k_gemm1(float* a,                 // acc1 / hh2
                                               const float* __restrict__ ch,
                                               const float* __restrict__ W1,
                                               const float* __restrict__ b1) {
    __shared__ float sW[DD * DD];
    __shared__ float sRow[4][DD];
    int tid = threadIdx.x;
    for (int i = tid; i < DD * DD / 4; i += 128)
        ((float4*)sW)[i] = ((const float4*)W1)[i];
    float bb = b1[tid];
    __syncthreads();
    for (int r0 = blockIdx.x * 4; r0 < N_HYPER; r0 += gridDim.x * 4) {
        __syncthreads();
#pragma unroll
        for (int r = 0; r < 4; ++r)
            sRow[r][tid] = a[(r0 + r) * DD + tid] * ch[r0 + r];
        __syncthreads();
        float acc[4] = {0, 0, 0, 0};
#pragma unroll 4
        for (int k = 0; k < DD; ++k) {
            float w = sW[k * DD + tid];
            acc[0] += sRow[0][k] * w;
            acc[1] += sRow[1][k] * w;
            acc[2] += sRow[2][k] * w;
            acc[3] += sRow[3][k] * w;
        }
#pragma unroll
        for (int r = 0; r < 4; ++r)
            a[(r0 + r) * DD + tid] = (acc[r] + bb) * ch[r0 + r];
    }
}

// ---------------- scatter 2: acc2[src] += hh2[dst] ----------------
__global__ void k_scatter2(const float* __restrict__ hh2, const int* __restrict__ src,
                           const int* __restrict__ dst, float* __restrict__ acc2) {
    int tt = blockIdx.x * 256 + threadIdx.x;
    int e = tt >> 5, c = tt & 31;
    if (e >= N_EDGES) return;
    int s = src[e], d = dst[e];
    const float4 v = *(const float4*)(hh2 + d * DD + c * 4);
    float* p = acc2 + s * DD + c * 4;
    atomicAdd(p + 0, v.x);
    atomicAdd(p + 1, v.y);
    atomicAdd(p + 2, v.z);
    atomicAdd(p + 3, v.w);
}

// --- GEMM2 + residual + LN1 (in-place): a := LN(h + (a*cn)@W2 + b2) ---------
__global__ __launch_bounds__(128) void k_gemm2_ln(float* a,              // acc2 / h1
                                                  const float* __restrict__ cn,
                                                  const float* __restrict__ W2,
                                                  const float* __restrict__ b2,
                                                  const float* __restrict__ h,
                                                  const float* __restrict__ gamma1,
                                                  const float* __restrict__ beta1) {
    __shared__ float sW[DD * DD];
    __shared__ float sRow[4][DD];
    __shared__ float sP[2][8];
    int tid = threadIdx.x;
    int wave = tid >> 6, lane = tid & 63;
    for (int i = tid; i < DD * DD / 4; i += 128)
        ((float4*)sW)[i] = ((const float4*)W2)[i];
    float bb = b2[tid], g = gamma1[tid], be = beta1[tid];
    __syncthreads();
    for (int r0 = blockIdx.x * 4; r0 < N_NODES; r0 += gridDim.x * 4) {
        __syncthreads();
#pragma unroll
        for (int r = 0; r < 4; ++r)
            sRow[r][tid] = a[(r0 + r) * DD + tid] * cn[r0 + r];
        __syncthreads();
        float acc[4] = {0, 0, 0, 0};
#pragma unroll 4
        for (int k = 0; k < DD; ++k) {
            float w = sW[k * DD + tid];
            acc[0] += sRow[0][k] * w;
            acc[1] += sRow[1][k] * w;
            acc[2] += sRow[2][k] * w;
            acc[3] += sRow[3][k] * w;
        }
        float t[4], s1[4], s2[4];
#pragma unroll
        for (int r = 0; r < 4; ++r) {
            t[r] = h[(r0 + r) * DD + tid] + acc[r] + bb;
            s1[r] = t[r]; s2[r] = t[r] * t[r];
        }
#pragma unroll
        for (int off = 32; off > 0; off >>= 1) {
#pragma unroll
            for (int r = 0; r < 4; ++r) {
                s1[r] += __shfl_down(s1[r], off, 64);
                s2[r] += __shfl_down(s2[r], off, 64);
            }
        }
        if (lane == 0) {
#pragma unroll
            for (int r = 0; r < 4; ++r) { sP[wave][r] = s1[r]; sP[wave][4 + r] = s2[r]; }
        }
        __syncthreads();
#pragma unroll
        for (int r = 0; r < 4; ++r) {
            float sum = sP[0][r] + sP[1][r];
            float sq  = sP[0][4 + r] + sP[1][4 + r];
            float mu  = sum * (1.f / 128.f);
            float var = sq * (1.f / 128.f) - mu * mu;
            float rs  = rsqrtf(var + 1e-5f);
            a[(r0 + r) * DD + tid] = (t[r] - mu) * rs * g + be;
        }
    }
}

// ------- FFN + residual + LN2: out = LN(h1 + relu(h1@W3+b3)@W4 + b4) --------
// block: 256 threads, 32 rows; W3/W4 streamed through LDS in 64-col/row chunks
__global__ __launch_bounds__(256) void k_ffn_ln(const float* __restrict__ h1,
                                                const float* __restrict__ W3,
                                                const float* __restrict__ b3,
                                                const float* __restrict__ W4,
                                                const float* __restrict__ b4,
                                                const float* __restrict__ gamma2,
                                                const float* __restrict__ beta2,
                                                float* __restrict__ out) {
    __shared__ float sA[32 * 132];
    __shared__ float sW[128 * 64];   // W3 chunk [128][64] OR W4 chunk [64][128]
    __shared__ float sY[32 * 65];
    int tid = threadIdx.x;
    int r0 = blockIdx.x * 32;
    // stage h1 tile (32 rows x 128 cols), float4
    for (int i = tid; i < 32 * 32; i += 256) {
        int r = i >> 5, c4 = i & 31;
        *(float4*)(&sA[r * 132 + c4 * 4]) = *(const float4*)(h1 + (r0 + r) * 128 + c4 * 4);
    }
    int cq = tid & 15;   // stage1: cols cq*4..+3 ; stage2/epilogue: cols cq*8..+7
    int rp = tid >> 4;   // rows 2rp, 2rp+1
    float o[2][8];
#pragma unroll
    for (int i = 0; i < 2; ++i)
#pragma unroll
        for (int j = 0; j < 8; ++j) o[i][j] = 0.f;
    __syncthreads();

    for (int nc = 0; nc < 8; ++nc) {
        __syncthreads();
        // load W3[:, nc*64 .. +63] -> sW[128][64]
        for (int i = tid; i < 128 * 16; i += 256) {
            int k = i >> 4, c4 = i & 15;
            *(float4*)(&sW[k * 64 + c4 * 4]) = *(const float4*)(W3 + k * 512 + nc * 64 + c4 * 4);
        }
        __syncthreads();
        float y0[4] = {0, 0, 0, 0}, y1[4] = {0, 0, 0, 0};
        const float* a0p = &sA[(2 * rp) * 132];
        const float* a1p = &sA[(2 * rp + 1) * 132];
        const float4* wv = (const float4*)sW;
#pragma unroll 4
        for (int k = 0; k < 128; ++k) {
            float a0 = a0p[k], a1 = a1p[k];
            float4 w = wv[k * 16 + cq];
            y0[0] += a0 * w.x; y0[1] += a0 * w.y; y0[2] += a0 * w.z; y0[3] += a0 * w.w;
            y1[0] += a1 * w.x; y1[1] += a1 * w.y; y1[2] += a1 * w.z; y1[3] += a1 * w.w;
        }
#pragma unroll
        for (int j = 0; j < 4; ++j) {
            float bb = b3[nc * 64 + cq * 4 + j];
            sY[(2 * rp) * 65 + cq * 4 + j]     = fmaxf(y0[j] + bb, 0.f);
            sY[(2 * rp + 1) * 65 + cq * 4 + j] = fmaxf(y1[j] + bb, 0.f);
        }
        __syncthreads();
        // load W4[nc*64 .. +63, :] -> sW[64][128]
        for (int i = tid; i < 64 * 32; i += 256) {
            int kk = i >> 5, c4 = i & 31;
            *(float4*)(&sW[kk * 128 + c4 * 4]) = *(const float4*)(W4 + (nc * 64 + kk) * 128 + c4 * 4);
        }
        __syncthreads();
        const float4* w4v = (const float4*)sW;
        const float* yp0 = &sY[(2 * rp) * 65];
        const float* yp1 = &sY[(2 * rp + 1) * 65];
#pragma unroll 2
        for (int kk = 0; kk < 64; ++kk) {
            float v0 = yp0[kk], v1 = yp1[kk];
            float4 wa = w4v[kk * 32 + cq * 2];
            float4 wb = w4v[kk * 32 + cq * 2 + 1];
            o[0][0] += v0 * wa.x; o[0][1] += v0 * wa.y; o[0][2] += v0 * wa.z; o[0][3] += v0 * wa.w;
            o[0][4] += v0 * wb.x; o[0][5] += v0 * wb.y; o[0][6] += v0 * wb.z; o[0][7] += v0 * wb.w;
            o[1][0] += v1 * wa.x; o[1][1] += v1 * wa.y; o[1][2] += v1 * wa.z; o[1][3] += v1 * wa.w;
            o[1][4] += v1 * wb.x; o[1][5] += v1 * wb.y; o[1][6] += v1 * wb.z; o[1][7] += v1 * wb.w;
        }
    }
    // epilogue: t = o + b4 + h1 ; per-row LN reduced over 16 consecutive lanes
    int col0 = cq * 8;
    float t[2][8], s1[2] = {0, 0}, s2[2] = {0, 0};
#pragma unroll
    for (int i = 0; i < 2; ++i) {
        const float* ap = &sA[(2 * rp + i) * 132];
#pragma unroll
        for (int j = 0; j < 8; ++j) {
            float v = o[i][j] + b4[col0 + j] + ap[col0 + j];
            t[i][j] = v; s1[i] += v; s2[i] += v * v;
        }
    }
#pragma unroll
    for (int off = 1; off < 16; off <<= 1) {
        s1[0] += __shfl_xor(s1[0], off, 64); s2[0] += __shfl_xor(s2[0], off, 64);
        s1[1] += __shfl_xor(s1[1], off, 64); s2[1] += __shfl_xor(s2[1], off, 64);
    }
#pragma unroll
    for (int i = 0; i < 2; ++i) {
        int row = r0 + 2 * rp + i;
        float mu  = s1[i] * (1.f / 128.f);
        float var = s2[i] * (1.f / 128.f) - mu * mu;
        float rs  = rsqrtf(var + 1e-5f);
        float4 v0, v1;
        v0.x = (t[i][0] - mu) * rs * gamma2[col0 + 0] + beta2[col0 + 0];
        v0.y = (t[i][1] - mu) * rs * gamma2[col0 + 1] + beta2[col0 + 1];
        v0.z = (t[i][2] - mu) * rs * gamma2[col0 + 2] + beta2[col0 + 2];
        v0.w = (t[i][3] - mu) * rs * gamma2[col0 + 3] + beta2[col0 + 3];
        v1.x = (t[i][4] - mu) * rs * gamma2[col0 + 4] + beta2[col0 + 4];
        v1.y = (t[i][5] - mu) * rs * gamma2[col0 + 5] + beta2[col0 + 5];
        v1.z = (t[i][6] - mu) * rs * gamma2[col0 + 6] + beta2[col0 + 6];
        v1.w = (t[i][7] - mu) * rs * gamma2[col0 + 7] + beta2[col0 + 7];
        *(float4*)(out + row * 128 + col0)     = v0;
        *(float4*)(out + row * 128 + col0 + 4) = v1;
    }
}

extern "C" void kernel_launch(void* const* d_in, const int* in_sizes, int n_in,
                              void* d_out, int out_size, void* d_ws, size_t ws_size,
                              hipStream_t stream) {
    const float* h      = (const float*)d_in[0];
    const int*   src    = (const int*)d_in[1];
    const int*   dst    = (const int*)d_in[2];
    const float* W1     = (const float*)d_in[3];
    const float* b1     = (const float*)d_in[4];
    const float* W2     = (const float*)d_in[5];
    const float* b2     = (const float*)d_in[6];
    const float* W3     = (const float*)d_in[7];
    const float* b3     = (const float*)d_in[8];
    const float* W4     = (const float*)d_in[9];
    const float* b4     = (const float*)d_in[10];
    const float* gamma1 = (const float*)d_in[11];
    const float* beta1  = (const float*)d_in[12];
    const float* gamma2 = (const float*)d_in[13];
    const float* beta2  = (const float*)d_in[14];
    float* out = (float*)d_out;

    // ws layout (bytes):
    // cn        f32[100000]      @ 0
    // ch        f32[20000]       @ 400000
    // acc1/hh2  f32[20000*128]   @ 480000      (GEMM1 runs in-place)
    // acc2/h1   f32[100000*128]  @ 10720000    (GEMM2+LN runs in-place)
    // total: 61,920,000 bytes
    char* ws = (char*)d_ws;
    float* cn   = (float*)(ws + 0);
    float* ch   = (float*)(ws + 400000);
    float* acc1 = (float*)(ws + 480000);
    float* acc2 = (float*)(ws + 10720000);

    hipMemsetAsync(d_ws, 0, 61920000, stream);

    k_deg<<<6250, 256, 0, stream>>>(src, dst, cn, ch);
    k_rsqrt<<<391, 256, 0, stream>>>(cn, ch);
    k_scatter1<<<200000, 256, 0, stream>>>(h, src, dst, cn, acc1);
    k_gemm1<<<2500, 128, 0, stream>>>(acc1, ch, W1, b1);
    k_scatter2<<<200000, 256, 0, stream>>>(acc1, src, dst, acc2);
    k_gemm2_ln<<<2048, 128, 0, stream>>>(acc2, cn, W2, b2, h, gamma1, beta1);
    k_ffn_ln<<<3125, 256, 0, stream>>>(acc2, W3, b3, W4, b4, gamma2, beta2, out);
}

// Round 3
// 1884.901 us; speedup vs baseline: 3.5082x; 3.5082x over previous
//
#include <hip/hip_runtime.h>

#define N_NODES 100000
#define N_HYPER 20000
#define N_EDGES 1600000
#define DD 128

// ---------------- CSR build: histogram ----------------
// ptr_node / ptr_he start as zeroed counters
__global__ void k_hist(const int* __restrict__ src, const int* __restrict__ dst,
                       int* __restrict__ cnt_node, int* __restrict__ cnt_he) {
    int e = blockIdx.x * 256 + threadIdx.x;
    if (e < N_EDGES) {
        atomicAdd(&cnt_node[src[e]], 1);
        atomicAdd(&cnt_he[dst[e]], 1);
    }
}

// ---------------- CSR build: in-place exclusive scan + rsqrt(deg) -----------
// a[i]: count -> exclusive start offset ; invsq[i] = rsqrt(max(count,1))
__global__ __launch_bounds__(1024) void k_scan(int* __restrict__ a,
                                               float* __restrict__ invsq, int n) {
    __shared__ int sums[1024];
    int tid = threadIdx.x;
    int chunk = (n + 1023) >> 10;
    int lo = tid * chunk;
    int hi = lo + chunk; if (hi > n) hi = n;
    int s = 0;
    for (int i = lo; i < hi; ++i) s += a[i];
    sums[tid] = s;
    __syncthreads();
    for (int off = 1; off < 1024; off <<= 1) {
        int t = (tid >= off) ? sums[tid - off] : 0;
        __syncthreads();
        sums[tid] += t;
        __syncthreads();
    }
    int running = sums[tid] - s;   // exclusive prefix of this thread's chunk
    for (int i = lo; i < hi; ++i) {
        int d = a[i];
        invsq[i] = rsqrtf((float)(d < 1 ? 1 : d));
        a[i] = running;
        running += d;
    }
}

// ---------------- CSR build: fill adjacency ----------------
// ptr arrays are cursors (atomically advanced); after this kernel
// ptr[i] == end offset of row i, and start(i) = (i ? ptr[i-1] : 0).
__global__ void k_fill(const int* __restrict__ src, const int* __restrict__ dst,
                       int* __restrict__ ptr_node, int* __restrict__ ptr_he,
                       int* __restrict__ adj_node, int* __restrict__ adj_he) {
    int e = blockIdx.x * 256 + threadIdx.x;
    if (e >= N_EDGES) return;
    int s = src[e], d = dst[e];
    int p1 = atomicAdd(&ptr_he[d], 1);
    adj_he[p1] = s;
    int p2 = atomicAdd(&ptr_node[s], 1);
    adj_node[p2] = d;
}

// ------- gather 1: acc1[d] = sum_{s in adj_he[d]} h[s] * cn[s] --------------
// one wave per hyperedge row; lane handles float2 at col lane*2
__global__ __launch_bounds__(256) void k_gather1(const float* __restrict__ h,
                                                 const int* __restrict__ adj,
                                                 const int* __restrict__ ptr,
                                                 const float* __restrict__ cn,
                                                 float* __restrict__ acc1) {
    int row = blockIdx.x * 4 + (threadIdx.x >> 6);
    int lane = threadIdx.x & 63;
    if (row >= N_HYPER) return;
    int start = (row == 0) ? 0 : ptr[row - 1];
    int end = ptr[row];
    const float2* hp = (const float2*)h;
    float ax = 0.f, ay = 0.f;
    int j = start;
    for (; j + 1 < end; j += 2) {
        int s0 = adj[j], s1 = adj[j + 1];
        float w0 = cn[s0], w1 = cn[s1];
        float2 v0 = hp[s0 * 64 + lane];
        float2 v1 = hp[s1 * 64 + lane];
        ax += v0.x * w0; ay += v0.y * w0;
        ax += v1.x * w1; ay += v1.y * w1;
    }
    if (j < end) {
        int s0 = adj[j];
        float w0 = cn[s0];
        float2 v0 = hp[s0 * 64 + lane];
        ax += v0.x * w0; ay += v0.y * w0;
    }
    float2 r; r.x = ax; r.y = ay;
    ((float2*)acc1)[row * 64 + lane] = r;
}

// ------- gather 2: acc2[s] = sum_{d in adj_node[s]} hh2[d] ------------------
__global__ __launch_bounds__(256) void k_gather2(const float* __restrict__ hh2,
                                                 const int* __restrict__ adj,
                                                 const int* __restrict__ ptr,
                                                 float* __restrict__ acc2) {
    int row = blockIdx.x * 4 + (threadIdx.x >> 6);
    int lane = threadIdx.x & 63;
    if (row >= N_NODES) return;
    int start = (row == 0) ? 0 : ptr[row - 1];
    int end = ptr[row];
    const float2* hp = (const float2*)hh2;
    float ax = 0.f, ay = 0.f;
    int j = start;
    for (; j + 1 < end; j += 2) {
        int d0 = adj[j], d1 = adj[j + 1];
        float2 v0 = hp[d0 * 64 + lane];
        float2 v1 = hp[d1 * 64 + lane];
        ax += v0.x + v1.x; ay += v0.y + v1.y;
    }
    if (j < end) {
        int d0 = adj[j];
        float2 v0 = hp[d0 * 64 + lane];
        ax += v0.x; ay += v0.y;
    }
    float2 r; r.x = ax; r.y = ay;
    ((float2*)acc2)[row * 64 + lane] = r;
}

// ------- GEMM1 (in-place): a := ((a*ch) @ W1 + b1) * ch  --------------------
__global__ __launch_bounds__(128) void k_gemm1(float* a,                 // acc1 / hh2
                                               const float* __restrict__ ch,
                                               const float* __restrict__ W1,
                                               const float* __restrict__ b1) {
    __shared__ float sW[DD * DD];
    __shared__ float sRow[4][DD];
    int tid = threadIdx.x;
    for (int i = tid; i < DD * DD / 4; i += 128)
        ((float4*)sW)[i] = ((const float4*)W1)[i];
    float bb = b1[tid];
    __syncthreads();
    for (int r0 = blockIdx.x * 4; r0 < N_HYPER; r0 += gridDim.x * 4) {
        __syncthreads();
#pragma unroll
        for (int r = 0; r < 4; ++r)
            sRow[r][tid] = a[(r0 + r) * DD + tid] * ch[r0 + r];
        __syncthreads();
        float acc[4] = {0, 0, 0, 0};
#pragma unroll 4
        for (int k = 0; k < DD; ++k) {
            float w = sW[k * DD + tid];
            acc[0] += sRow[0][k] * w;
            acc[1] += sRow[1][k] * w;
            acc[2] += sRow[2][k] * w;
            acc[3] += sRow[3][k] * w;
        }
#pragma unroll
        for (int r = 0; r < 4; ++r)
            a[(r0 + r) * DD + tid] = (acc[r] + bb) * ch[r0 + r];
    }
}

// --- GEMM2 + residual + LN1 (in-place): a := LN(h + (a*cn)@W2 + b2) ---------
__global__ __launch_bounds__(128) void k_gemm2_ln(float* a,              // acc2 / h1
                                                  const float* __restrict__ cn,
                                                  const float* __restrict__ W2,
                                                  const float* __restrict__ b2,
                                                  const float* __restrict__ h,
                                                  const float* __restrict__ gamma1,
                                                  const float* __restrict__ beta1) {
    __shared__ float sW[DD * DD];
    __shared__ float sRow[4][DD];
    __shared__ float sP[2][8];
    int tid = threadIdx.x;
    int wave = tid >> 6, lane = tid & 63;
    for (int i = tid; i < DD * DD / 4; i += 128)
        ((float4*)sW)[i] = ((const float4*)W2)[i];
    float bb = b2[tid], g = gamma1[tid], be = beta1[tid];
    __syncthreads();
    for (int r0 = blockIdx.x * 4; r0 < N_NODES; r0 += gridDim.x * 4) {
        __syncthreads();
#pragma unroll
        for (int r = 0; r < 4; ++r)
            sRow[r][tid] = a[(r0 + r) * DD + tid] * cn[r0 + r];
        __syncthreads();
        float acc[4] = {0, 0, 0, 0};
#pragma unroll 4
        for (int k = 0; k < DD; ++k) {
            float w = sW[k * DD + tid];
            acc[0] += sRow[0][k] * w;
            acc[1] += sRow[1][k] * w;
            acc[2] += sRow[2][k] * w;
            acc[3] += sRow[3][k] * w;
        }
        float t[4], s1[4], s2[4];
#pragma unroll
        for (int r = 0; r < 4; ++r) {
            t[r] = h[(r0 + r) * DD + tid] + acc[r] + bb;
            s1[r] = t[r]; s2[r] = t[r] * t[r];
        }
#pragma unroll
        for (int off = 32; off > 0; off >>= 1) {
#pragma unroll
            for (int r = 0; r < 4; ++r) {
                s1[r] += __shfl_down(s1[r], off, 64);
                s2[r] += __shfl_down(s2[r], off, 64);
            }
        }
        if (lane == 0) {
#pragma unroll
            for (int r = 0; r < 4; ++r) { sP[wave][r] = s1[r]; sP[wave][4 + r] = s2[r]; }
        }
        __syncthreads();
#pragma unroll
        for (int r = 0; r < 4; ++r) {
            float sum = sP[0][r] + sP[1][r];
            float sq  = sP[0][4 + r] + sP[1][4 + r];
            float mu  = sum * (1.f / 128.f);
            float var = sq * (1.f / 128.f) - mu * mu;
            float rs  = rsqrtf(var + 1e-5f);
            a[(r0 + r) * DD + tid] = (t[r] - mu) * rs * g + be;
        }
    }
}

// ------- FFN + residual + LN2: out = LN(h1 + relu(h1@W3+b3)@W4 + b4) --------
__global__ __launch_bounds__(256) void k_ffn_ln(const float* __restrict__ h1,
                                                const float* __restrict__ W3,
                                                const float* __restrict__ b3,
                                                const float* __restrict__ W4,
                                                const float* __restrict__ b4,
                                                const float* __restrict__ gamma2,
                                                const float* __restrict__ beta2,
                                                float* __restrict__ out) {
    __shared__ float sA[32 * 132];
    __shared__ float sW[128 * 64];   // W3 chunk [128][64] OR W4 chunk [64][128]
    __shared__ float sY[32 * 65];
    int tid = threadIdx.x;
    int r0 = blockIdx.x * 32;
    for (int i = tid; i < 32 * 32; i += 256) {
        int r = i >> 5, c4 = i & 31;
        *(float4*)(&sA[r * 132 + c4 * 4]) = *(const float4*)(h1 + (r0 + r) * 128 + c4 * 4);
    }
    int cq = tid & 15;
    int rp = tid >> 4;
    float o[2][8];
#pragma unroll
    for (int i = 0; i < 2; ++i)
#pragma unroll
        for (int j = 0; j < 8; ++j) o[i][j] = 0.f;
    __syncthreads();

    for (int nc = 0; nc < 8; ++nc) {
        __syncthreads();
        for (int i = tid; i < 128 * 16; i += 256) {
            int k = i >> 4, c4 = i & 15;
            *(float4*)(&sW[k * 64 + c4 * 4]) = *(const float4*)(W3 + k * 512 + nc * 64 + c4 * 4);
        }
        __syncthreads();
        float y0[4] = {0, 0, 0, 0}, y1[4] = {0, 0, 0, 0};
        const float* a0p = &sA[(2 * rp) * 132];
        const float* a1p = &sA[(2 * rp + 1) * 132];
        const float4* wv = (const float4*)sW;
#pragma unroll 4
        for (int k = 0; k < 128; ++k) {
            float a0 = a0p[k], a1 = a1p[k];
            float4 w = wv[k * 16 + cq];
            y0[0] += a0 * w.x; y0[1] += a0 * w.y; y0[2] += a0 * w.z; y0[3] += a0 * w.w;
            y1[0] += a1 * w.x; y1[1] += a1 * w.y; y1[2] += a1 * w.z; y1[3] += a1 * w.w;
        }
#pragma unroll
        for (int j = 0; j < 4; ++j) {
            float bb = b3[nc * 64 + cq * 4 + j];
            sY[(2 * rp) * 65 + cq * 4 + j]     = fmaxf(y0[j] + bb, 0.f);
            sY[(2 * rp + 1) * 65 + cq * 4 + j] = fmaxf(y1[j] + bb, 0.f);
        }
        __syncthreads();
        for (int i = tid; i < 64 * 32; i += 256) {
            int kk = i >> 5, c4 = i & 31;
            *(float4*)(&sW[kk * 128 + c4 * 4]) = *(const float4*)(W4 + (nc * 64 + kk) * 128 + c4 * 4);
        }
        __syncthreads();
        const float4* w4v = (const float4*)sW;
        const float* yp0 = &sY[(2 * rp) * 65];
        const float* yp1 = &sY[(2 * rp + 1) * 65];
#pragma unroll 2
        for (int kk = 0; kk < 64; ++kk) {
            float v0 = yp0[kk], v1 = yp1[kk];
            float4 wa = w4v[kk * 32 + cq * 2];
            float4 wb = w4v[kk * 32 + cq * 2 + 1];
            o[0][0] += v0 * wa.x; o[0][1] += v0 * wa.y; o[0][2] += v0 * wa.z; o[0][3] += v0 * wa.w;
            o[0][4] += v0 * wb.x; o[0][5] += v0 * wb.y; o[0][6] += v0 * wb.z; o[0][7] += v0 * wb.w;
            o[1][0] += v1 * wa.x; o[1][1] += v1 * wa.y; o[1][2] += v1 * wa.z; o[1][3] += v1 * wa.w;
            o[1][4] += v1 * wb.x; o[1][5] += v1 * wb.y; o[1][6] += v1 * wb.z; o[1][7] += v1 * wb.w;
        }
    }
    int col0 = cq * 8;
    float t[2][8], s1[2] = {0, 0}, s2[2] = {0, 0};
#pragma unroll
    for (int i = 0; i < 2; ++i) {
        const float* ap = &sA[(2 * rp + i) * 132];
#pragma unroll
        for (int j = 0; j < 8; ++j) {
            float v = o[i][j] + b4[col0 + j] + ap[col0 + j];
            t[i][j] = v; s1[i] += v; s2[i] += v * v;
        }
    }
#pragma unroll
    for (int off = 1; off < 16; off <<= 1) {
        s1[0] += __shfl_xor(s1[0], off, 64); s2[0] += __shfl_xor(s2[0], off, 64);
        s1[1] += __shfl_xor(s1[1], off, 64); s2[1] += __shfl_xor(s2[1], off, 64);
    }
#pragma unroll
    for (int i = 0; i < 2; ++i) {
        int row = r0 + 2 * rp + i;
        float mu  = s1[i] * (1.f / 128.f);
        float var = s2[i] * (1.f / 128.f) - mu * mu;
        float rs  = rsqrtf(var + 1e-5f);
        float4 v0, v1;
        v0.x = (t[i][0] - mu) * rs * gamma2[col0 + 0] + beta2[col0 + 0];
        v0.y = (t[i][1] - mu) * rs * gamma2[col0 + 1] + beta2[col0 + 1];
        v0.z = (t[i][2] - mu) * rs * gamma2[col0 + 2] + beta2[col0 + 2];
        v0.w = (t[i][3] - mu) * rs * gamma2[col0 + 3] + beta2[col0 + 3];
        v1.x = (t[i][4] - mu) * rs * gamma2[col0 + 4] + beta2[col0 + 4];
        v1.y = (t[i][5] - mu) * rs * gamma2[col0 + 5] + beta2[col0 + 5];
        v1.z = (t[i][6] - mu) * rs * gamma2[col0 + 6] + beta2[col0 + 6];
        v1.w = (t[i][7] - mu) * rs * gamma2[col0 + 7] + beta2[col0 + 7];
        *(float4*)(out + row * 128 + col0)     = v0;
        *(float4*)(out + row * 128 + col0 + 4) = v1;
    }
}

extern "C" void kernel_launch(void* const* d_in, const int* in_sizes, int n_in,
                              void* d_out, int out_size, void* d_ws, size_t ws_size,
                              hipStream_t stream) {
    const float* h      = (const float*)d_in[0];
    const int*   src    = (const int*)d_in[1];
    const int*   dst    = (const int*)d_in[2];
    const float* W1     = (const float*)d_in[3];
    const float* b1     = (const float*)d_in[4];
    const float* W2     = (const float*)d_in[5];
    const float* b2     = (const float*)d_in[6];
    const float* W3     = (const float*)d_in[7];
    const float* b3     = (const float*)d_in[8];
    const float* W4     = (const float*)d_in[9];
    const float* b4     = (const float*)d_in[10];
    const float* gamma1 = (const float*)d_in[11];
    const float* beta1  = (const float*)d_in[12];
    const float* gamma2 = (const float*)d_in[13];
    const float* beta2  = (const float*)d_in[14];
    float* out = (float*)d_out;

    // ws layout (bytes):
    // ptr_node int[100000]   @ 0           (counter -> scan -> cursor -> row ends)
    // ptr_he   int[20000]    @ 400000
    // adj_he   int[1.6M]     @ 480000      (src ids grouped by dst)
    // adj_node int[1.6M]     @ 6880000     (dst ids grouped by src)
    // cn       f32[100000]   @ 13280000
    // ch       f32[20000]    @ 13680000
    // acc1/hh2 f32[20000*128]  @ 13760000  (gather1 out; gemm1 in-place)
    // acc2/h1  f32[100000*128] @ 24000000  (gather2 out; gemm2+LN in-place)
    // total: 75,200,000 bytes
    char* ws = (char*)d_ws;
    int*   ptr_node = (int*)(ws + 0);
    int*   ptr_he   = (int*)(ws + 400000);
    int*   adj_he   = (int*)(ws + 480000);
    int*   adj_node = (int*)(ws + 6880000);
    float* cn       = (float*)(ws + 13280000);
    float* ch       = (float*)(ws + 13680000);
    float* acc1     = (float*)(ws + 13760000);
    float* acc2     = (float*)(ws + 24000000);

    hipMemsetAsync(d_ws, 0, 480000, stream);   // zero the two counter arrays only

    k_hist<<<6250, 256, 0, stream>>>(src, dst, ptr_node, ptr_he);
    k_scan<<<1, 1024, 0, stream>>>(ptr_node, cn, N_NODES);
    k_scan<<<1, 1024, 0, stream>>>(ptr_he, ch, N_HYPER);
    k_fill<<<6250, 256, 0, stream>>>(src, dst, ptr_node, ptr_he, adj_node, adj_he);
    k_gather1<<<5000, 256, 0, stream>>>(h, adj_he, ptr_he, cn, acc1);
    k_gemm1<<<2500, 128, 0, stream>>>(acc1, ch, W1, b1);
    k_gather2<<<25000, 256, 0, stream>>>(acc1, adj_node, ptr_node, acc2);
    k_gemm2_ln<<<2048, 128, 0, stream>>>(acc2, cn, W2, b2, h, gamma1, beta1);
    k_ffn_ln<<<3125, 256, 0, stream>>>(acc2, W3, b3, W4, b4, gamma2, beta2, out);
}

// Round 5
// 1147.326 us; speedup vs baseline: 5.7635x; 1.6429x over previous
//
#include <hip/hip_runtime.h>

#define N_NODES 100000
#define N_HYPER 20000
#define N_EDGES 1600000
#define LDW 136   // LDS row stride in bf16 elems: 272 B = odd*16B (16B-aligned, bank-decorrelated)

typedef unsigned short u16;
typedef short bf16x8 __attribute__((ext_vector_type(8)));
typedef float f32x4 __attribute__((ext_vector_type(4)));

__device__ __forceinline__ f32x4 mfma16(bf16x8 a, bf16x8 b, f32x4 c) {
    return __builtin_amdgcn_mfma_f32_16x16x32_bf16(a, b, c, 0, 0, 0);
}
__device__ __forceinline__ u16 f2bf(float f) {
    unsigned u = __float_as_uint(f);
    unsigned r = u + 0x7FFFu + ((u >> 16) & 1u);   // RN-even
    return (u16)(r >> 16);
}

// ---------------- weight prep: bf16 + transpose (N-major, K-contiguous) -----
__global__ __launch_bounds__(256) void k_prep(const float* __restrict__ W1, const float* __restrict__ W2,
                                              const float* __restrict__ W3, const float* __restrict__ W4,
                                              u16* __restrict__ W1t, u16* __restrict__ W2t,
                                              u16* __restrict__ W3t, u16* __restrict__ W4t) {
    int i = blockIdx.x * 256 + threadIdx.x;
    if (i < 16384) {
        int k = i & 127, n = i >> 7;
        W1t[n * 128 + k] = f2bf(W1[k * 128 + n]);
        W2t[n * 128 + k] = f2bf(W2[k * 128 + n]);
    }
    if (i < 65536) {
        int k = i & 127, n = i >> 7;          // n < 512
        W3t[n * 128 + k] = f2bf(W3[k * 512 + n]);
        int k4 = i & 511, n4 = i >> 9;        // n4 < 128
        W4t[n4 * 512 + k4] = f2bf(W4[k4 * 128 + n4]);
    }
}

// ---------------- CSR build: histogram ----------------
__global__ void k_hist(const int* __restrict__ src, const int* __restrict__ dst,
                       int* __restrict__ cnt_node, int* __restrict__ cnt_he) {
    int e = blockIdx.x * 256 + threadIdx.x;
    if (e < N_EDGES) {
        atomicAdd(&cnt_node[src[e]], 1);
        atomicAdd(&cnt_he[dst[e]], 1);
    }
}

// ---------------- CSR build: in-place exclusive scan + rsqrt(deg) -----------
__global__ __launch_bounds__(1024) void k_scan(int* __restrict__ a,
                                               float* __restrict__ invsq, int n) {
    __shared__ int sums[1024];
    int tid = threadIdx.x;
    int chunk = (n + 1023) >> 10;
    int lo = tid * chunk;
    int hi = lo + chunk; if (hi > n) hi = n;
    int s = 0;
    for (int i = lo; i < hi; ++i) s += a[i];
    sums[tid] = s;
    __syncthreads();
    for (int off = 1; off < 1024; off <<= 1) {
        int t = (tid >= off) ? sums[tid - off] : 0;
        __syncthreads();
        sums[tid] += t;
        __syncthreads();
    }
    int running = sums[tid] - s;
    for (int i = lo; i < hi; ++i) {
        int d = a[i];
        invsq[i] = rsqrtf((float)(d < 1 ? 1 : d));
        a[i] = running;
        running += d;
    }
}

// ---------------- CSR build: fill adjacency ----------------
__global__ void k_fill(const int* __restrict__ src, const int* __restrict__ dst,
                       int* __restrict__ ptr_node, int* __restrict__ ptr_he,
                       int* __restrict__ adj_node, int* __restrict__ adj_he) {
    int e = blockIdx.x * 256 + threadIdx.x;
    if (e >= N_EDGES) return;
    int s = src[e], d = dst[e];
    int p1 = atomicAdd(&ptr_he[d], 1);
    adj_he[p1] = s;
    int p2 = atomicAdd(&ptr_node[s], 1);
    adj_node[p2] = d;
}

// ------- gather 1: acc1[d] = sum_{s in adj_he[d]} h[s] * cn[s] --------------
__global__ __launch_bounds__(256) void k_gather1(const float* __restrict__ h,
                                                 const int* __restrict__ adj,
                                                 const int* __restrict__ ptr,
                                                 const float* __restrict__ cn,
                                                 float* __restrict__ acc1) {
    int row = blockIdx.x * 4 + (threadIdx.x >> 6);
    int lane = threadIdx.x & 63;
    if (row >= N_HYPER) return;
    int start = (row == 0) ? 0 : ptr[row - 1];
    int end = ptr[row];
    const float2* hp = (const float2*)h;
    float ax = 0.f, ay = 0.f;
    int j = start;
    for (; j + 1 < end; j += 2) {
        int s0 = adj[j], s1 = adj[j + 1];
        float w0 = cn[s0], w1 = cn[s1];
        float2 v0 = hp[s0 * 64 + lane];
        float2 v1 = hp[s1 * 64 + lane];
        ax += v0.x * w0; ay += v0.y * w0;
        ax += v1.x * w1; ay += v1.y * w1;
    }
    if (j < end) {
        int s0 = adj[j];
        float w0 = cn[s0];
        float2 v0 = hp[s0 * 64 + lane];
        ax += v0.x * w0; ay += v0.y * w0;
    }
    float2 r; r.x = ax; r.y = ay;
    ((float2*)acc1)[row * 64 + lane] = r;
}

// ------- gather 2: acc2[s] = sum_{d in adj_node[s]} hh2[d] ------------------
__global__ __launch_bounds__(256) void k_gather2(const float* __restrict__ hh2,
                                                 const int* __restrict__ adj,
                                                 const int* __restrict__ ptr,
                                                 float* __restrict__ acc2) {
    int row = blockIdx.x * 4 + (threadIdx.x >> 6);
    int lane = threadIdx.x & 63;
    if (row >= N_NODES) return;
    int start = (row == 0) ? 0 : ptr[row - 1];
    int end = ptr[row];
    const float2* hp = (const float2*)hh2;
    float ax = 0.f, ay = 0.f;
    int j = start;
    for (; j + 1 < end; j += 2) {
        int d0 = adj[j], d1 = adj[j + 1];
        float2 v0 = hp[d0 * 64 + lane];
        float2 v1 = hp[d1 * 64 + lane];
        ax += v0.x + v1.x; ay += v0.y + v1.y;
    }
    if (j < end) {
        int d0 = adj[j];
        float2 v0 = hp[d0 * 64 + lane];
        ax += v0.x; ay += v0.y;
    }
    float2 r; r.x = ax; r.y = ay;
    ((float2*)acc2)[row * 64 + lane] = r;
}

// ------- GEMM1 (MFMA, in-place): a := ((a*ch) @ W1 + b1) * ch ---------------
__global__ __launch_bounds__(256) void k_gemm1(float* a, const float* __restrict__ ch,
                                               const u16* __restrict__ W1t,
                                               const float* __restrict__ b1) {
    __shared__ u16 sA[64 * LDW];
    __shared__ u16 sW[128 * LDW];
    int tid = threadIdx.x;
    int r0 = blockIdx.x * 64;
    for (int i = tid; i < 64 * 32; i += 256) {
        int r = i >> 5, c4 = i & 31;
        int row = r0 + r; if (row > N_HYPER - 1) row = N_HYPER - 1;
        float4 v = *(const float4*)(a + row * 128 + c4 * 4);
        float cw = ch[row];
        u16* p = &sA[r * LDW + c4 * 4];
        p[0] = f2bf(v.x * cw); p[1] = f2bf(v.y * cw);
        p[2] = f2bf(v.z * cw); p[3] = f2bf(v.w * cw);
    }
    for (int i = tid; i < 128 * 16; i += 256) {
        int n = i >> 4, c = i & 15;
        *(uint4*)&sW[n * LDW + c * 8] = *(const uint4*)(W1t + n * 128 + c * 8);
    }
    __syncthreads();
    int w = tid >> 6, l15 = tid & 15, quad = (tid & 63) >> 4;
    f32x4 zero = {0.f, 0.f, 0.f, 0.f};
    f32x4 acc[8];
#pragma unroll
    for (int nt = 0; nt < 8; ++nt) acc[nt] = zero;
    int arow = w * 16 + l15;
#pragma unroll
    for (int kt = 0; kt < 4; ++kt) {
        bf16x8 af = *(bf16x8*)&sA[arow * LDW + kt * 32 + quad * 8];
#pragma unroll
        for (int nt = 0; nt < 8; ++nt) {
            bf16x8 bfv = *(bf16x8*)&sW[(nt * 16 + l15) * LDW + kt * 32 + quad * 8];
            acc[nt] = mfma16(af, bfv, acc[nt]);
        }
    }
#pragma unroll
    for (int r = 0; r < 4; ++r) {
        int row = r0 + w * 16 + quad * 4 + r;
        if (row < N_HYPER) {
            float cw = ch[row];
#pragma unroll
            for (int nt = 0; nt < 8; ++nt) {
                int n = nt * 16 + l15;
                a[row * 128 + n] = (acc[nt][r] + b1[n]) * cw;
            }
        }
    }
}

// --- GEMM2 + residual + LN1 (MFMA, in-place): a := LN(h + (a*cn)@W2 + b2) ---
__global__ __launch_bounds__(256) void k_gemm2_ln(float* a, const float* __restrict__ cn,
                                                  const u16* __restrict__ W2t,
                                                  const float* __restrict__ b2,
                                                  const float* __restrict__ h,
                                                  const float* __restrict__ gamma1,
                                                  const float* __restrict__ beta1) {
    __shared__ u16 sA[64 * LDW];
    __shared__ u16 sW[128 * LDW];
    int tid = threadIdx.x;
    int r0 = blockIdx.x * 64;
    for (int i = tid; i < 64 * 32; i += 256) {
        int r = i >> 5, c4 = i & 31;
        int row = r0 + r; if (row > N_NODES - 1) row = N_NODES - 1;
        float4 v = *(const float4*)(a + row * 128 + c4 * 4);
        float cw = cn[row];
        u16* p = &sA[r * LDW + c4 * 4];
        p[0] = f2bf(v.x * cw); p[1] = f2bf(v.y * cw);
        p[2] = f2bf(v.z * cw); p[3] = f2bf(v.w * cw);
    }
    for (int i = tid; i < 128 * 16; i += 256) {
        int n = i >> 4, c = i & 15;
        *(uint4*)&sW[n * LDW + c * 8] = *(const uint4*)(W2t + n * 128 + c * 8);
    }
    __syncthreads();
    int w = tid >> 6, l15 = tid & 15, quad = (tid & 63) >> 4;
    f32x4 zero = {0.f, 0.f, 0.f, 0.f};
    f32x4 acc[8];
#pragma unroll
    for (int nt = 0; nt < 8; ++nt) acc[nt] = zero;
    int arow = w * 16 + l15;
#pragma unroll
    for (int kt = 0; kt < 4; ++kt) {
        bf16x8 af = *(bf16x8*)&sA[arow * LDW + kt * 32 + quad * 8];
#pragma unroll
        for (int nt = 0; nt < 8; ++nt) {
            bf16x8 bfv = *(bf16x8*)&sW[(nt * 16 + l15) * LDW + kt * 32 + quad * 8];
            acc[nt] = mfma16(af, bfv, acc[nt]);
        }
    }
    // epilogue: t = acc + b2 + h ; LN over each row (16 lanes of a quad hold it)
    float s1[4] = {0, 0, 0, 0}, s2[4] = {0, 0, 0, 0};
#pragma unroll
    for (int r = 0; r < 4; ++r) {
        int row = r0 + w * 16 + quad * 4 + r;
        int rc = row > N_NODES - 1 ? N_NODES - 1 : row;
#pragma unroll
        for (int nt = 0; nt < 8; ++nt) {
            int n = nt * 16 + l15;
            float t = acc[nt][r] + b2[n] + h[rc * 128 + n];
            acc[nt][r] = t;
            s1[r] += t; s2[r] += t * t;
        }
    }
#pragma unroll
    for (int off = 1; off < 16; off <<= 1) {
#pragma unroll
        for (int r = 0; r < 4; ++r) {
            s1[r] += __shfl_xor(s1[r], off, 64);
            s2[r] += __shfl_xor(s2[r], off, 64);
        }
    }
#pragma unroll
    for (int r = 0; r < 4; ++r) {
        int row = r0 + w * 16 + quad * 4 + r;
        if (row < N_NODES) {
            float mu = s1[r] * (1.f / 128.f);
            float var = s2[r] * (1.f / 128.f) - mu * mu;
            float rs = rsqrtf(var + 1e-5f);
#pragma unroll
            for (int nt = 0; nt < 8; ++nt) {
                int n = nt * 16 + l15;
                a[row * 128 + n] = (acc[nt][r] - mu) * rs * gamma1[n] + beta1[n];
            }
        }
    }
}

// ------- FFN + residual + LN2 (MFMA): out = LN(h1 + relu(h1@W3+b3)@W4+b4) ---
__global__ __launch_bounds__(256) void k_ffn_ln(const float* __restrict__ h1,
                                                const u16* __restrict__ W3t,
                                                const float* __restrict__ b3,
                                                const u16* __restrict__ W4t,
                                                const float* __restrict__ b4,
                                                const float* __restrict__ gamma2,
                                                const float* __restrict__ beta2,
                                                float* __restrict__ out) {
    __shared__ u16 sA[64 * LDW];
    __shared__ u16 sW[128 * LDW];
    __shared__ u16 sY[64 * LDW];
    int tid = threadIdx.x;
    int r0 = blockIdx.x * 64;
    for (int i = tid; i < 64 * 32; i += 256) {
        int r = i >> 5, c4 = i & 31;
        int row = r0 + r; if (row > N_NODES - 1) row = N_NODES - 1;
        float4 v = *(const float4*)(h1 + row * 128 + c4 * 4);
        u16* p = &sA[r * LDW + c4 * 4];
        p[0] = f2bf(v.x); p[1] = f2bf(v.y); p[2] = f2bf(v.z); p[3] = f2bf(v.w);
    }
    int w = tid >> 6, l15 = tid & 15, quad = (tid & 63) >> 4;
    int arow = w * 16 + l15;
    f32x4 zero = {0.f, 0.f, 0.f, 0.f};
    f32x4 acc[8];
#pragma unroll
    for (int nt = 0; nt < 8; ++nt) acc[nt] = zero;

    for (int nc = 0; nc < 4; ++nc) {
        __syncthreads();   // prev chunk's sW/sY reads done (also covers sA staging on nc=0)
        for (int i = tid; i < 128 * 16; i += 256) {
            int n = i >> 4, c = i & 15;
            *(uint4*)&sW[n * LDW + c * 8] = *(const uint4*)(W3t + (nc * 128 + n) * 128 + c * 8);
        }
        __syncthreads();
        // stage 1: Y = relu(A @ W3chunk + b3)
        f32x4 y[8];
#pragma unroll
        for (int nt = 0; nt < 8; ++nt) y[nt] = zero;
#pragma unroll
        for (int kt = 0; kt < 4; ++kt) {
            bf16x8 af = *(bf16x8*)&sA[arow * LDW + kt * 32 + quad * 8];
#pragma unroll
            for (int nt = 0; nt < 8; ++nt) {
                bf16x8 bfv = *(bf16x8*)&sW[(nt * 16 + l15) * LDW + kt * 32 + quad * 8];
                y[nt] = mfma16(af, bfv, y[nt]);
            }
        }
#pragma unroll
        for (int r = 0; r < 4; ++r) {
            int yrow = w * 16 + quad * 4 + r;
#pragma unroll
            for (int nt = 0; nt < 8; ++nt) {
                int n = nt * 16 + l15;
                float vv = y[nt][r] + b3[nc * 128 + n];
                sY[yrow * LDW + n] = f2bf(vv > 0.f ? vv : 0.f);
            }
        }
        __syncthreads();   // sY complete; stage-1 sW reads done
        for (int i = tid; i < 128 * 16; i += 256) {
            int n = i >> 4, c = i & 15;
            *(uint4*)&sW[n * LDW + c * 8] = *(const uint4*)(W4t + n * 512 + nc * 128 + c * 8);
        }
        __syncthreads();
        // stage 2: acc += Y @ W4chunk
#pragma unroll
        for (int kt = 0; kt < 4; ++kt) {
            bf16x8 af = *(bf16x8*)&sY[arow * LDW + kt * 32 + quad * 8];
#pragma unroll
            for (int nt = 0; nt < 8; ++nt) {
                bf16x8 bfv = *(bf16x8*)&sW[(nt * 16 + l15) * LDW + kt * 32 + quad * 8];
                acc[nt] = mfma16(af, bfv, acc[nt]);
            }
        }
    }
    // epilogue: t = acc + b4 + h1 ; LN2
    float s1[4] = {0, 0, 0, 0}, s2[4] = {0, 0, 0, 0};
#pragma unroll
    for (int r = 0; r < 4; ++r) {
        int row = r0 + w * 16 + quad * 4 + r;
        int rc = row > N_NODES - 1 ? N_NODES - 1 : row;
#pragma unroll
        for (int nt = 0; nt < 8; ++nt) {
            int n = nt * 16 + l15;
            float t = acc[nt][r] + b4[n] + h1[rc * 128 + n];
            acc[nt][r] = t;
            s1[r] += t; s2[r] += t * t;
        }
    }
#pragma unroll
    for (int off = 1; off < 16; off <<= 1) {
#pragma unroll
        for (int r = 0; r < 4; ++r) {
            s1[r] += __shfl_xor(s1[r], off, 64);
            s2[r] += __shfl_xor(s2[r], off, 64);
        }
    }
#pragma unroll
    for (int r = 0; r < 4; ++r) {
        int row = r0 + w * 16 + quad * 4 + r;
        if (row < N_NODES) {
            float mu = s1[r] * (1.f / 128.f);
            float var = s2[r] * (1.f / 128.f) - mu * mu;
            float rs = rsqrtf(var + 1e-5f);
#pragma unroll
            for (int nt = 0; nt < 8; ++nt) {
                int n = nt * 16 + l15;
                out[row * 128 + n] = (acc[nt][r] - mu) * rs * gamma2[n] + beta2[n];
            }
        }
    }
}

extern "C" void kernel_launch(void* const* d_in, const int* in_sizes, int n_in,
                              void* d_out, int out_size, void* d_ws, size_t ws_size,
                              hipStream_t stream) {
    const float* h      = (const float*)d_in[0];
    const int*   src    = (const int*)d_in[1];
    const int*   dst    = (const int*)d_in[2];
    const float* W1     = (const float*)d_in[3];
    const float* b1     = (const float*)d_in[4];
    const float* W2     = (const float*)d_in[5];
    const float* b2     = (const float*)d_in[6];
    const float* W3     = (const float*)d_in[7];
    const float* b3     = (const float*)d_in[8];
    const float* W4     = (const float*)d_in[9];
    const float* b4     = (const float*)d_in[10];
    const float* gamma1 = (const float*)d_in[11];
    const float* beta1  = (const float*)d_in[12];
    const float* gamma2 = (const float*)d_in[13];
    const float* beta2  = (const float*)d_in[14];
    float* out = (float*)d_out;

    // ws layout (bytes):
    // ptr_node int[100000]     @ 0
    // ptr_he   int[20000]      @ 400000
    // adj_he   int[1.6M]       @ 480000
    // adj_node int[1.6M]       @ 6880000
    // cn       f32[100000]     @ 13280000
    // ch       f32[20000]      @ 13680000
    // acc1/hh2 f32[20000*128]  @ 13760000   (gemm1 in-place)
    // acc2/h1  f32[100000*128] @ 24000000   (gemm2+LN in-place)
    // W1t bf16[128*128]        @ 75200000
    // W2t bf16[128*128]        @ 75232768
    // W3t bf16[512*128]        @ 75265536
    // W4t bf16[128*512]        @ 75396608   (end 75527680)
    char* ws = (char*)d_ws;
    int*   ptr_node = (int*)(ws + 0);
    int*   ptr_he   = (int*)(ws + 400000);
    int*   adj_he   = (int*)(ws + 480000);
    int*   adj_node = (int*)(ws + 6880000);
    float* cn       = (float*)(ws + 13280000);
    float* ch       = (float*)(ws + 13680000);
    float* acc1     = (float*)(ws + 13760000);
    float* acc2     = (float*)(ws + 24000000);
    u16*   W1t      = (u16*)(ws + 75200000);
    u16*   W2t      = (u16*)(ws + 75232768);
    u16*   W3t      = (u16*)(ws + 75265536);
    u16*   W4t      = (u16*)(ws + 75396608);

    hipMemsetAsync(d_ws, 0, 480000, stream);   // zero the two counter arrays only

    k_prep<<<256, 256, 0, stream>>>(W1, W2, W3, W4, W1t, W2t, W3t, W4t);
    k_hist<<<6250, 256, 0, stream>>>(src, dst, ptr_node, ptr_he);
    k_scan<<<1, 1024, 0, stream>>>(ptr_node, cn, N_NODES);
    k_scan<<<1, 1024, 0, stream>>>(ptr_he, ch, N_HYPER);
    k_fill<<<6250, 256, 0, stream>>>(src, dst, ptr_node, ptr_he, adj_node, adj_he);
    k_gather1<<<5000, 256, 0, stream>>>(h, adj_he, ptr_he, cn, acc1);
    k_gemm1<<<313, 256, 0, stream>>>(acc1, ch, W1t, b1);
    k_gather2<<<25000, 256, 0, stream>>>(acc1, adj_node, ptr_node, acc2);
    k_gemm2_ln<<<1563, 256, 0, stream>>>(acc2, cn, W2t, b2, h, gamma1, beta1);
    k_ffn_ln<<<1563, 256, 0, stream>>>(acc2, W3t, b3, W4t, b4, gamma2, beta2, out);
}

// Round 6
// 931.565 us; speedup vs baseline: 7.0984x; 1.2316x over previous
//
#include <hip/hip_runtime.h>

#define N_NODES 100000
#define N_HYPER 20000
#define N_EDGES 1600000
#define LDW 136   // LDS row stride in bf16 elems: 272 B = odd*16B (16B-aligned, bank-decorrelated)

typedef unsigned short u16;
typedef unsigned int u32;
typedef short bf16x8 __attribute__((ext_vector_type(8)));
typedef float f32x4 __attribute__((ext_vector_type(4)));

__device__ __forceinline__ f32x4 mfma16(bf16x8 a, bf16x8 b, f32x4 c) {
    return __builtin_amdgcn_mfma_f32_16x16x32_bf16(a, b, c, 0, 0, 0);
}
__device__ __forceinline__ u16 f2bf(float f) {
    unsigned u = __float_as_uint(f);
    unsigned r = u + 0x7FFFu + ((u >> 16) & 1u);   // RN-even
    return (u16)(r >> 16);
}
__device__ __forceinline__ void bfu(unsigned v, float& f0, float& f1) {
    f0 = __uint_as_float(v << 16);
    f1 = __uint_as_float(v & 0xFFFF0000u);
}

// ------- weight prep (bf16, N-major K-contiguous) + h -> bf16 copy ----------
__global__ __launch_bounds__(256) void k_prep(const float* __restrict__ W1, const float* __restrict__ W2,
                                              const float* __restrict__ W3, const float* __restrict__ W4,
                                              u16* __restrict__ W1t, u16* __restrict__ W2t,
                                              u16* __restrict__ W3t, u16* __restrict__ W4t,
                                              const float* __restrict__ h, u16* __restrict__ h_bf) {
    int i = blockIdx.x * 256 + threadIdx.x;
    if (i < 16384) {
        int k = i & 127, n = i >> 7;
        W1t[n * 128 + k] = f2bf(W1[k * 128 + n]);
        W2t[n * 128 + k] = f2bf(W2[k * 128 + n]);
    }
    if (i < 65536) {
        int k = i & 127, n = i >> 7;          // n < 512
        W3t[n * 128 + k] = f2bf(W3[k * 512 + n]);
        int k4 = i & 511, n4 = i >> 9;        // n4 < 128
        W4t[n4 * 512 + k4] = f2bf(W4[k4 * 128 + n4]);
    }
    if (i < 3276800) {                        // 12.8M elems / 4
        float4 v = ((const float4*)h)[i];
        uint2 st;
        st.x = (u32)f2bf(v.x) | ((u32)f2bf(v.y) << 16);
        st.y = (u32)f2bf(v.z) | ((u32)f2bf(v.w) << 16);
        ((uint2*)h_bf)[i] = st;
    }
}

// ------- CSR build: histogram, XCD-windowed (group g owns 1/8 id range) -----
__global__ __launch_bounds__(256) void k_hist(const int* __restrict__ src, const int* __restrict__ dst,
                                              int* __restrict__ cnt_node, int* __restrict__ cnt_he) {
    int g = blockIdx.x & 7;
    int node_lo = g * (N_NODES / 8), node_hi = node_lo + N_NODES / 8;
    int he_lo = g * (N_HYPER / 8), he_hi = he_lo + N_HYPER / 8;
    int stride = (gridDim.x >> 3) * 256;
    for (int e = (blockIdx.x >> 3) * 256 + threadIdx.x; e < N_EDGES; e += stride) {
        int s = src[e], d = dst[e];
        if (s >= node_lo && s < node_hi) atomicAdd(&cnt_node[s], 1);
        if (d >= he_lo && d < he_hi) atomicAdd(&cnt_he[d], 1);
    }
}

// ------- CSR build: in-place exclusive scan + rsqrt(deg) --------------------
__global__ __launch_bounds__(1024) void k_scan(int* __restrict__ a,
                                               float* __restrict__ invsq, int n) {
    __shared__ int sums[1024];
    int tid = threadIdx.x;
    int chunk = (n + 1023) >> 10;
    int lo = tid * chunk;
    int hi = lo + chunk; if (hi > n) hi = n;
    int s = 0;
    for (int i = lo; i < hi; ++i) s += a[i];
    sums[tid] = s;
    __syncthreads();
    for (int off = 1; off < 1024; off <<= 1) {
        int t = (tid >= off) ? sums[tid - off] : 0;
        __syncthreads();
        sums[tid] += t;
        __syncthreads();
    }
    int running = sums[tid] - s;
    for (int i = lo; i < hi; ++i) {
        int d = a[i];
        invsq[i] = rsqrtf((float)(d < 1 ? 1 : d));
        a[i] = running;
        running += d;
    }
}

// ------- CSR build: fill adjacency, XCD-windowed ----------------------------
// Group g writes only its contiguous slice of each adjacency array, so the
// active write window (~0.8-1.6 MB) stays L2-resident and lines fill fully.
__global__ __launch_bounds__(256) void k_fill(const int* __restrict__ src, const int* __restrict__ dst,
                                              int* __restrict__ ptr_node, int* __restrict__ ptr_he,
                                              int* __restrict__ adj_node, int* __restrict__ adj_he) {
    int g = blockIdx.x & 7;
    int node_lo = g * (N_NODES / 8), node_hi = node_lo + N_NODES / 8;
    int he_lo = g * (N_HYPER / 8), he_hi = he_lo + N_HYPER / 8;
    int stride = (gridDim.x >> 3) * 256;
    for (int e = (blockIdx.x >> 3) * 256 + threadIdx.x; e < N_EDGES; e += stride) {
        int s = src[e], d = dst[e];
        if (d >= he_lo && d < he_hi) {
            int p = atomicAdd(&ptr_he[d], 1);
            adj_he[p] = s;
        }
        if (s >= node_lo && s < node_hi) {
            int p = atomicAdd(&ptr_node[s], 1);
            adj_node[p] = d;
        }
    }
}

// ------- gather 1: acc1[d] = sum_{s in adj_he[d]} h_bf[s] * cn[s] -----------
// one wave per row; lane = (p = edge parity, c = uint2 column); 2 edges/iter x2 unroll
__global__ __launch_bounds__(256) void k_gather1(const u16* __restrict__ h_bf,
                                                 const int* __restrict__ adj,
                                                 const int* __restrict__ ptr,
                                                 const float* __restrict__ cn,
                                                 float* __restrict__ acc1) {
    int row = blockIdx.x * 4 + (threadIdx.x >> 6);
    int lane = threadIdx.x & 63;
    int p = lane >> 5, c = lane & 31;
    int start = (row == 0) ? 0 : ptr[row - 1];
    int end = ptr[row];
    const uint2* hp = (const uint2*)h_bf;
    float A0[4] = {0, 0, 0, 0}, A1[4] = {0, 0, 0, 0};
    float f0, f1, f2, f3;
    int j = start;
    for (; j + 3 < end; j += 4) {
        int sA = adj[j + p], sB = adj[j + 2 + p];
        float wA = cn[sA], wB = cn[sB];
        uint2 vA = hp[sA * 32 + c];
        uint2 vB = hp[sB * 32 + c];
        bfu(vA.x, f0, f1); bfu(vA.y, f2, f3);
        A0[0] += f0 * wA; A0[1] += f1 * wA; A0[2] += f2 * wA; A0[3] += f3 * wA;
        bfu(vB.x, f0, f1); bfu(vB.y, f2, f3);
        A1[0] += f0 * wB; A1[1] += f1 * wB; A1[2] += f2 * wB; A1[3] += f3 * wB;
    }
    for (; j + 1 < end; j += 2) {
        int sA = adj[j + p];
        float wA = cn[sA];
        uint2 vA = hp[sA * 32 + c];
        bfu(vA.x, f0, f1); bfu(vA.y, f2, f3);
        A0[0] += f0 * wA; A0[1] += f1 * wA; A0[2] += f2 * wA; A0[3] += f3 * wA;
    }
    if (j < end && p == 0) {
        int sA = adj[j];
        float wA = cn[sA];
        uint2 vA = hp[sA * 32 + c];
        bfu(vA.x, f0, f1); bfu(vA.y, f2, f3);
        A0[0] += f0 * wA; A0[1] += f1 * wA; A0[2] += f2 * wA; A0[3] += f3 * wA;
    }
    float r0 = A0[0] + A1[0], r1 = A0[1] + A1[1], r2 = A0[2] + A1[2], r3 = A0[3] + A1[3];
    r0 += __shfl_xor(r0, 32, 64);
    r1 += __shfl_xor(r1, 32, 64);
    r2 += __shfl_xor(r2, 32, 64);
    r3 += __shfl_xor(r3, 32, 64);
    if (p == 0) {
        float4 o; o.x = r0; o.y = r1; o.z = r2; o.w = r3;
        ((float4*)acc1)[row * 32 + c] = o;
    }
}

// ------- gather 2: acc2[s] = sum_{d in adj_node[s]} hh2b[d] -----------------
__global__ __launch_bounds__(256) void k_gather2(const u16* __restrict__ hh2b,
                                                 const int* __restrict__ adj,
                                                 const int* __restrict__ ptr,
                                                 float* __restrict__ acc2) {
    int row = blockIdx.x * 4 + (threadIdx.x >> 6);
    int lane = threadIdx.x & 63;
    int p = lane >> 5, c = lane & 31;
    int start = (row == 0) ? 0 : ptr[row - 1];
    int end = ptr[row];
    const uint2* hp = (const uint2*)hh2b;
    float A0[4] = {0, 0, 0, 0}, A1[4] = {0, 0, 0, 0};
    float f0, f1, f2, f3;
    int j = start;
    for (; j + 3 < end; j += 4) {
        int dA = adj[j + p], dB = adj[j + 2 + p];
        uint2 vA = hp[dA * 32 + c];
        uint2 vB = hp[dB * 32 + c];
        bfu(vA.x, f0, f1); bfu(vA.y, f2, f3);
        A0[0] += f0; A0[1] += f1; A0[2] += f2; A0[3] += f3;
        bfu(vB.x, f0, f1); bfu(vB.y, f2, f3);
        A1[0] += f0; A1[1] += f1; A1[2] += f2; A1[3] += f3;
    }
    for (; j + 1 < end; j += 2) {
        int dA = adj[j + p];
        uint2 vA = hp[dA * 32 + c];
        bfu(vA.x, f0, f1); bfu(vA.y, f2, f3);
        A0[0] += f0; A0[1] += f1; A0[2] += f2; A0[3] += f3;
    }
    if (j < end && p == 0) {
        int dA = adj[j];
        uint2 vA = hp[dA * 32 + c];
        bfu(vA.x, f0, f1); bfu(vA.y, f2, f3);
        A0[0] += f0; A0[1] += f1; A0[2] += f2; A0[3] += f3;
    }
    float r0 = A0[0] + A1[0], r1 = A0[1] + A1[1], r2 = A0[2] + A1[2], r3 = A0[3] + A1[3];
    r0 += __shfl_xor(r0, 32, 64);
    r1 += __shfl_xor(r1, 32, 64);
    r2 += __shfl_xor(r2, 32, 64);
    r3 += __shfl_xor(r3, 32, 64);
    if (p == 0) {
        float4 o; o.x = r0; o.y = r1; o.z = r2; o.w = r3;
        ((float4*)acc2)[row * 32 + c] = o;
    }
}

// ------- GEMM1 (MFMA): hh2b = bf16(((acc1*ch) @ W1 + b1) * ch) --------------
__global__ __launch_bounds__(256) void k_gemm1(const float* __restrict__ a, const float* __restrict__ ch,
                                               const u16* __restrict__ W1t,
                                               const float* __restrict__ b1,
                                               u16* __restrict__ hh2b) {
    __shared__ u16 sA[64 * LDW];
    __shared__ u16 sW[128 * LDW];
    int tid = threadIdx.x;
    int r0 = blockIdx.x * 64;
    for (int i = tid; i < 64 * 32; i += 256) {
        int r = i >> 5, c4 = i & 31;
        int row = r0 + r; if (row > N_HYPER - 1) row = N_HYPER - 1;
        float4 v = *(const float4*)(a + row * 128 + c4 * 4);
        float cw = ch[row];
        u16* p = &sA[r * LDW + c4 * 4];
        p[0] = f2bf(v.x * cw); p[1] = f2bf(v.y * cw);
        p[2] = f2bf(v.z * cw); p[3] = f2bf(v.w * cw);
    }
    for (int i = tid; i < 128 * 16; i += 256) {
        int n = i >> 4, c = i & 15;
        *(uint4*)&sW[n * LDW + c * 8] = *(const uint4*)(W1t + n * 128 + c * 8);
    }
    __syncthreads();
    int w = tid >> 6, l15 = tid & 15, quad = (tid & 63) >> 4;
    f32x4 zero = {0.f, 0.f, 0.f, 0.f};
    f32x4 acc[8];
#pragma unroll
    for (int nt = 0; nt < 8; ++nt) acc[nt] = zero;
    int arow = w * 16 + l15;
#pragma unroll
    for (int kt = 0; kt < 4; ++kt) {
        bf16x8 af = *(bf16x8*)&sA[arow * LDW + kt * 32 + quad * 8];
#pragma unroll
        for (int nt = 0; nt < 8; ++nt) {
            bf16x8 bfv = *(bf16x8*)&sW[(nt * 16 + l15) * LDW + kt * 32 + quad * 8];
            acc[nt] = mfma16(af, bfv, acc[nt]);
        }
    }
#pragma unroll
    for (int r = 0; r < 4; ++r) {
        int row = r0 + w * 16 + quad * 4 + r;
        if (row < N_HYPER) {
            float cw = ch[row];
#pragma unroll
            for (int nt = 0; nt < 8; ++nt) {
                int n = nt * 16 + l15;
                hh2b[row * 128 + n] = f2bf((acc[nt][r] + b1[n]) * cw);
            }
        }
    }
}

// --- GEMM2 + residual + LN1 (MFMA, in-place): a := LN(h + (a*cn)@W2 + b2) ---
__global__ __launch_bounds__(256) void k_gemm2_ln(float* a, const float* __restrict__ cn,
                                                  const u16* __restrict__ W2t,
                                                  const float* __restrict__ b2,
                                                  const float* __restrict__ h,
                                                  const float* __restrict__ gamma1,
                                                  const float* __restrict__ beta1) {
    __shared__ u16 sA[64 * LDW];
    __shared__ u16 sW[128 * LDW];
    int tid = threadIdx.x;
    int r0 = blockIdx.x * 64;
    for (int i = tid; i < 64 * 32; i += 256) {
        int r = i >> 5, c4 = i & 31;
        int row = r0 + r; if (row > N_NODES - 1) row = N_NODES - 1;
        float4 v = *(const float4*)(a + row * 128 + c4 * 4);
        float cw = cn[row];
        u16* p = &sA[r * LDW + c4 * 4];
        p[0] = f2bf(v.x * cw); p[1] = f2bf(v.y * cw);
        p[2] = f2bf(v.z * cw); p[3] = f2bf(v.w * cw);
    }
    for (int i = tid; i < 128 * 16; i += 256) {
        int n = i >> 4, c = i & 15;
        *(uint4*)&sW[n * LDW + c * 8] = *(const uint4*)(W2t + n * 128 + c * 8);
    }
    __syncthreads();
    int w = tid >> 6, l15 = tid & 15, quad = (tid & 63) >> 4;
    f32x4 zero = {0.f, 0.f, 0.f, 0.f};
    f32x4 acc[8];
#pragma unroll
    for (int nt = 0; nt < 8; ++nt) acc[nt] = zero;
    int arow = w * 16 + l15;
#pragma unroll
    for (int kt = 0; kt < 4; ++kt) {
        bf16x8 af = *(bf16x8*)&sA[arow * LDW + kt * 32 + quad * 8];
#pragma unroll
        for (int nt = 0; nt < 8; ++nt) {
            bf16x8 bfv = *(bf16x8*)&sW[(nt * 16 + l15) * LDW + kt * 32 + quad * 8];
            acc[nt] = mfma16(af, bfv, acc[nt]);
        }
    }
    float s1[4] = {0, 0, 0, 0}, s2[4] = {0, 0, 0, 0};
#pragma unroll
    for (int r = 0; r < 4; ++r) {
        int row = r0 + w * 16 + quad * 4 + r;
        int rc = row > N_NODES - 1 ? N_NODES - 1 : row;
#pragma unroll
        for (int nt = 0; nt < 8; ++nt) {
            int n = nt * 16 + l15;
            float t = acc[nt][r] + b2[n] + h[rc * 128 + n];
            acc[nt][r] = t;
            s1[r] += t; s2[r] += t * t;
        }
    }
#pragma unroll
    for (int off = 1; off < 16; off <<= 1) {
#pragma unroll
        for (int r = 0; r < 4; ++r) {
            s1[r] += __shfl_xor(s1[r], off, 64);
            s2[r] += __shfl_xor(s2[r], off, 64);
        }
    }
#pragma unroll
    for (int r = 0; r < 4; ++r) {
        int row = r0 + w * 16 + quad * 4 + r;
        if (row < N_NODES) {
            float mu = s1[r] * (1.f / 128.f);
            float var = s2[r] * (1.f / 128.f) - mu * mu;
            float rs = rsqrtf(var + 1e-5f);
#pragma unroll
            for (int nt = 0; nt < 8; ++nt) {
                int n = nt * 16 + l15;
                a[row * 128 + n] = (acc[nt][r] - mu) * rs * gamma1[n] + beta1[n];
            }
        }
    }
}

// ------- FFN + residual + LN2 (MFMA): out = LN(h1 + relu(h1@W3+b3)@W4+b4) ---
__global__ __launch_bounds__(256) void k_ffn_ln(const float* __restrict__ h1,
                                                const u16* __restrict__ W3t,
                                                const float* __restrict__ b3,
                                                const u16* __restrict__ W4t,
                                                const float* __restrict__ b4,
                                                const float* __restrict__ gamma2,
                                                const float* __restrict__ beta2,
                                                float* __restrict__ out) {
    __shared__ u16 sA[64 * LDW];
    __shared__ u16 sW[128 * LDW];
    __shared__ u16 sY[64 * LDW];
    int tid = threadIdx.x;
    int r0 = blockIdx.x * 64;
    for (int i = tid; i < 64 * 32; i += 256) {
        int r = i >> 5, c4 = i & 31;
        int row = r0 + r; if (row > N_NODES - 1) row = N_NODES - 1;
        float4 v = *(const float4*)(h1 + row * 128 + c4 * 4);
        u16* p = &sA[r * LDW + c4 * 4];
        p[0] = f2bf(v.x); p[1] = f2bf(v.y); p[2] = f2bf(v.z); p[3] = f2bf(v.w);
    }
    int w = tid >> 6, l15 = tid & 15, quad = (tid & 63) >> 4;
    int arow = w * 16 + l15;
    f32x4 zero = {0.f, 0.f, 0.f, 0.f};
    f32x4 acc[8];
#pragma unroll
    for (int nt = 0; nt < 8; ++nt) acc[nt] = zero;

    for (int nc = 0; nc < 4; ++nc) {
        __syncthreads();
        for (int i = tid; i < 128 * 16; i += 256) {
            int n = i >> 4, c = i & 15;
            *(uint4*)&sW[n * LDW + c * 8] = *(const uint4*)(W3t + (nc * 128 + n) * 128 + c * 8);
        }
        __syncthreads();
        f32x4 y[8];
#pragma unroll
        for (int nt = 0; nt < 8; ++nt) y[nt] = zero;
#pragma unroll
        for (int kt = 0; kt < 4; ++kt) {
            bf16x8 af = *(bf16x8*)&sA[arow * LDW + kt * 32 + quad * 8];
#pragma unroll
            for (int nt = 0; nt < 8; ++nt) {
                bf16x8 bfv = *(bf16x8*)&sW[(nt * 16 + l15) * LDW + kt * 32 + quad * 8];
                y[nt] = mfma16(af, bfv, y[nt]);
            }
        }
#pragma unroll
        for (int r = 0; r < 4; ++r) {
            int yrow = w * 16 + quad * 4 + r;
#pragma unroll
            for (int nt = 0; nt < 8; ++nt) {
                int n = nt * 16 + l15;
                float vv = y[nt][r] + b3[nc * 128 + n];
                sY[yrow * LDW + n] = f2bf(vv > 0.f ? vv : 0.f);
            }
        }
        __syncthreads();
        for (int i = tid; i < 128 * 16; i += 256) {
            int n = i >> 4, c = i & 15;
            *(uint4*)&sW[n * LDW + c * 8] = *(const uint4*)(W4t + n * 512 + nc * 128 + c * 8);
        }
        __syncthreads();
#pragma unroll
        for (int kt = 0; kt < 4; ++kt) {
            bf16x8 af = *(bf16x8*)&sY[arow * LDW + kt * 32 + quad * 8];
#pragma unroll
            for (int nt = 0; nt < 8; ++nt) {
                bf16x8 bfv = *(bf16x8*)&sW[(nt * 16 + l15) * LDW + kt * 32 + quad * 8];
                acc[nt] = mfma16(af, bfv, acc[nt]);
            }
        }
    }
    float s1[4] = {0, 0, 0, 0}, s2[4] = {0, 0, 0, 0};
#pragma unroll
    for (int r = 0; r < 4; ++r) {
        int row = r0 + w * 16 + quad * 4 + r;
        int rc = row > N_NODES - 1 ? N_NODES - 1 : row;
#pragma unroll
        for (int nt = 0; nt < 8; ++nt) {
            int n = nt * 16 + l15;
            float t = acc[nt][r] + b4[n] + h1[rc * 128 + n];
            acc[nt][r] = t;
            s1[r] += t; s2[r] += t * t;
        }
    }
#pragma unroll
    for (int off = 1; off < 16; off <<= 1) {
#pragma unroll
        for (int r = 0; r < 4; ++r) {
            s1[r] += __shfl_xor(s1[r], off, 64);
            s2[r] += __shfl_xor(s2[r], off, 64);
        }
    }
#pragma unroll
    for (int r = 0; r < 4; ++r) {
        int row = r0 + w * 16 + quad * 4 + r;
        if (row < N_NODES) {
            float mu = s1[r] * (1.f / 128.f);
            float var = s2[r] * (1.f / 128.f) - mu * mu;
            float rs = rsqrtf(var + 1e-5f);
#pragma unroll
            for (int nt = 0; nt < 8; ++nt) {
                int n = nt * 16 + l15;
                out[row * 128 + n] = (acc[nt][r] - mu) * rs * gamma2[n] + beta2[n];
            }
        }
    }
}

extern "C" void kernel_launch(void* const* d_in, const int* in_sizes, int n_in,
                              void* d_out, int out_size, void* d_ws, size_t ws_size,
                              hipStream_t stream) {
    const float* h      = (const float*)d_in[0];
    const int*   src    = (const int*)d_in[1];
    const int*   dst    = (const int*)d_in[2];
    const float* W1     = (const float*)d_in[3];
    const float* b1     = (const float*)d_in[4];
    const float* W2     = (const float*)d_in[5];
    const float* b2     = (const float*)d_in[6];
    const float* W3     = (const float*)d_in[7];
    const float* b3     = (const float*)d_in[8];
    const float* W4     = (const float*)d_in[9];
    const float* b4     = (const float*)d_in[10];
    const float* gamma1 = (const float*)d_in[11];
    const float* beta1  = (const float*)d_in[12];
    const float* gamma2 = (const float*)d_in[13];
    const float* beta2  = (const float*)d_in[14];
    float* out = (float*)d_out;

    // ws layout (bytes), with dead-region aliasing:
    // ptr_node int[100000]     @ 0
    // ptr_he   int[20000]      @ 400000
    // adj_he   int[1.6M]       @ 480000    } hh2b bf16[20000*128] (5.12MB) aliases
    //                                      }   adj_he after gather1 is done
    // adj_node int[1.6M]       @ 6880000
    // cn       f32[100000]     @ 13280000
    // ch       f32[20000]      @ 13680000
    // acc1     f32[20000*128]  @ 13760000
    // acc2/h1  f32[100000*128] @ 24000000  } h_bf bf16[100000*128] (25.6MB) aliases
    //                                      }   acc2 until gather2 writes it
    // W1t bf16[128*128]        @ 75200000
    // W2t bf16[128*128]        @ 75232768
    // W3t bf16[512*128]        @ 75265536
    // W4t bf16[128*512]        @ 75396608   (end 75527680)
    char* ws = (char*)d_ws;
    int*   ptr_node = (int*)(ws + 0);
    int*   ptr_he   = (int*)(ws + 400000);
    int*   adj_he   = (int*)(ws + 480000);
    int*   adj_node = (int*)(ws + 6880000);
    float* cn       = (float*)(ws + 13280000);
    float* ch       = (float*)(ws + 13680000);
    float* acc1     = (float*)(ws + 13760000);
    float* acc2     = (float*)(ws + 24000000);
    u16*   W1t      = (u16*)(ws + 75200000);
    u16*   W2t      = (u16*)(ws + 75232768);
    u16*   W3t      = (u16*)(ws + 75265536);
    u16*   W4t      = (u16*)(ws + 75396608);
    u16*   h_bf     = (u16*)(ws + 24000000);   // alias acc2 (dead until gather2)
    u16*   hh2b     = (u16*)(ws + 480000);     // alias adj_he (dead after gather1)

    hipMemsetAsync(d_ws, 0, 480000, stream);   // zero the two counter arrays only

    k_prep<<<12800, 256, 0, stream>>>(W1, W2, W3, W4, W1t, W2t, W3t, W4t, h, h_bf);
    k_hist<<<832, 256, 0, stream>>>(src, dst, ptr_node, ptr_he);
    k_scan<<<1, 1024, 0, stream>>>(ptr_node, cn, N_NODES);
    k_scan<<<1, 1024, 0, stream>>>(ptr_he, ch, N_HYPER);
    k_fill<<<832, 256, 0, stream>>>(src, dst, ptr_node, ptr_he, adj_node, adj_he);
    k_gather1<<<5000, 256, 0, stream>>>(h_bf, adj_he, ptr_he, cn, acc1);
    k_gemm1<<<313, 256, 0, stream>>>(acc1, ch, W1t, b1, hh2b);
    k_gather2<<<25000, 256, 0, stream>>>(hh2b, adj_node, ptr_node, acc2);
    k_gemm2_ln<<<1563, 256, 0, stream>>>(acc2, cn, W2t, b2, h, gamma1, beta1);
    k_ffn_ln<<<1563, 256, 0, stream>>>(acc2, W3t, b3, W4t, b4, gamma2, beta2, out);
}

// Round 7
// 689.671 us; speedup vs baseline: 9.5881x; 1.3507x over previous
//
#include <hip/hip_runtime.h>

#define N_NODES 100000
#define N_HYPER 20000
#define N_EDGES 1600000
#define LDW 136   // LDS row stride in bf16 elems: 272 B = odd*16B (16B-aligned, bank-decorrelated)

typedef unsigned short u16;
typedef unsigned int u32;
typedef short bf16x8 __attribute__((ext_vector_type(8)));
typedef float f32x4 __attribute__((ext_vector_type(4)));

__device__ __forceinline__ f32x4 mfma16(bf16x8 a, bf16x8 b, f32x4 c) {
    return __builtin_amdgcn_mfma_f32_16x16x32_bf16(a, b, c, 0, 0, 0);
}
__device__ __forceinline__ u16 f2bf(float f) {
    unsigned u = __float_as_uint(f);
    unsigned r = u + 0x7FFFu + ((u >> 16) & 1u);   // RN-even
    return (u16)(r >> 16);
}
__device__ __forceinline__ void bfu(unsigned v, float& f0, float& f1) {
    f0 = __uint_as_float(v << 16);
    f1 = __uint_as_float(v & 0xFFFF0000u);
}

// ------- weight prep (bf16, N-major K-contiguous) + h -> bf16 copy ----------
__global__ __launch_bounds__(256) void k_prep(const float* __restrict__ W1, const float* __restrict__ W2,
                                              const float* __restrict__ W3, const float* __restrict__ W4,
                                              u16* __restrict__ W1t, u16* __restrict__ W2t,
                                              u16* __restrict__ W3t, u16* __restrict__ W4t,
                                              const float* __restrict__ h, u16* __restrict__ h_bf) {
    int i = blockIdx.x * 256 + threadIdx.x;
    if (i < 16384) {
        int k = i & 127, n = i >> 7;
        W1t[n * 128 + k] = f2bf(W1[k * 128 + n]);
        W2t[n * 128 + k] = f2bf(W2[k * 128 + n]);
    }
    if (i < 65536) {
        int k = i & 127, n = i >> 7;          // n < 512
        W3t[n * 128 + k] = f2bf(W3[k * 512 + n]);
        int k4 = i & 511, n4 = i >> 9;        // n4 < 128
        W4t[n4 * 512 + k4] = f2bf(W4[k4 * 128 + n4]);
    }
    if (i < 3276800) {                        // 12.8M elems / 4
        float4 v = ((const float4*)h)[i];
        uint2 st;
        st.x = (u32)f2bf(v.x) | ((u32)f2bf(v.y) << 16);
        st.y = (u32)f2bf(v.z) | ((u32)f2bf(v.w) << 16);
        ((uint2*)h_bf)[i] = st;
    }
}

// ------- CSR build: histogram, XCD-windowed (group g owns 1/8 id range) -----
__global__ __launch_bounds__(256) void k_hist(const int* __restrict__ src, const int* __restrict__ dst,
                                              int* __restrict__ cnt_node, int* __restrict__ cnt_he) {
    int g = blockIdx.x & 7;
    int node_lo = g * (N_NODES / 8), node_hi = node_lo + N_NODES / 8;
    int he_lo = g * (N_HYPER / 8), he_hi = he_lo + N_HYPER / 8;
    int stride = (gridDim.x >> 3) * 256;
    for (int e = (blockIdx.x >> 3) * 256 + threadIdx.x; e < N_EDGES; e += stride) {
        int s = src[e], d = dst[e];
        if (s >= node_lo && s < node_hi) atomicAdd(&cnt_node[s], 1);
        if (d >= he_lo && d < he_hi) atomicAdd(&cnt_he[d], 1);
    }
}

// ------- multi-block scan, phase A: per-block sums --------------------------
// blocks 0..24 -> node array (4096 elems each), blocks 25..29 -> he array
__global__ __launch_bounds__(256) void k_scanA(const int* __restrict__ a_node,
                                               const int* __restrict__ a_he,
                                               int* __restrict__ bs) {
    __shared__ int red[256];
    int b = blockIdx.x;
    const int* a; int base, n;
    if (b < 25) { a = a_node; base = b * 4096; n = N_NODES; }
    else        { a = a_he;   base = (b - 25) * 4096; n = N_HYPER; }
    int t = threadIdx.x;
    int lo = base + t * 16;
    int s = 0;
#pragma unroll
    for (int i = 0; i < 16; ++i) {
        int idx = lo + i;
        if (idx < n) s += a[idx];
    }
    red[t] = s;
    __syncthreads();
    for (int off = 128; off > 0; off >>= 1) {
        if (t < off) red[t] += red[t + off];
        __syncthreads();
    }
    if (t == 0) bs[b] = red[0];
}

// ------- phase B: exclusive scan of the 25+5 block sums ---------------------
__global__ void k_scanB(int* __restrict__ bs) {
    int t = threadIdx.x;
    if (t == 0) {
        int run = 0;
        for (int i = 0; i < 25; ++i) { int v = bs[i]; bs[i] = run; run += v; }
    } else if (t == 1) {
        int run = 0;
        for (int i = 25; i < 30; ++i) { int v = bs[i]; bs[i] = run; run += v; }
    }
}

// ------- phase C: block-local scan + apply base; emit offsets + rsqrt(deg) --
__global__ __launch_bounds__(256) void k_scanC(int* __restrict__ a_node, int* __restrict__ a_he,
                                               float* __restrict__ iq_node, float* __restrict__ iq_he,
                                               const int* __restrict__ bs) {
    __shared__ int pre[256];
    int b = blockIdx.x;
    int* a; float* iq; int base, n;
    if (b < 25) { a = a_node; iq = iq_node; base = b * 4096; n = N_NODES; }
    else        { a = a_he;   iq = iq_he;   base = (b - 25) * 4096; n = N_HYPER; }
    int t = threadIdx.x;
    int lo = base + t * 16;
    int loc = 0;
#pragma unroll
    for (int i = 0; i < 16; ++i) { int idx = lo + i; if (idx < n) loc += a[idx]; }
    pre[t] = loc;
    __syncthreads();
    for (int off = 1; off < 256; off <<= 1) {
        int v = (t >= off) ? pre[t - off] : 0;
        __syncthreads();
        pre[t] += v;
        __syncthreads();
    }
    int running = bs[b] + pre[t] - loc;   // global exclusive prefix for this thread
#pragma unroll
    for (int i = 0; i < 16; ++i) {
        int idx = lo + i;
        if (idx < n) {
            int d = a[idx];
            iq[idx] = rsqrtf((float)(d < 1 ? 1 : d));
            a[idx] = running;
            running += d;
        }
    }
}

// ------- CSR build: fill adjacency, XCD-windowed ----------------------------
__global__ __launch_bounds__(256) void k_fill(const int* __restrict__ src, const int* __restrict__ dst,
                                              int* __restrict__ ptr_node, int* __restrict__ ptr_he,
                                              int* __restrict__ adj_node, int* __restrict__ adj_he) {
    int g = blockIdx.x & 7;
    int node_lo = g * (N_NODES / 8), node_hi = node_lo + N_NODES / 8;
    int he_lo = g * (N_HYPER / 8), he_hi = he_lo + N_HYPER / 8;
    int stride = (gridDim.x >> 3) * 256;
    for (int e = (blockIdx.x >> 3) * 256 + threadIdx.x; e < N_EDGES; e += stride) {
        int s = src[e], d = dst[e];
        if (d >= he_lo && d < he_hi) {
            int p = atomicAdd(&ptr_he[d], 1);
            adj_he[p] = s;
        }
        if (s >= node_lo && s < node_hi) {
            int p = atomicAdd(&ptr_node[s], 1);
            adj_node[p] = d;
        }
    }
}

// ------- gather 1: acc1[d] = sum_{s in adj_he[d]} h_bf[s] * cn[s] -----------
__global__ __launch_bounds__(256) void k_gather1(const u16* __restrict__ h_bf,
                                                 const int* __restrict__ adj,
                                                 const int* __restrict__ ptr,
                                                 const float* __restrict__ cn,
                                                 float* __restrict__ acc1) {
    int row = blockIdx.x * 4 + (threadIdx.x >> 6);
    int lane = threadIdx.x & 63;
    int p = lane >> 5, c = lane & 31;
    int start = (row == 0) ? 0 : ptr[row - 1];
    int end = ptr[row];
    const uint2* hp = (const uint2*)h_bf;
    float A0[4] = {0, 0, 0, 0}, A1[4] = {0, 0, 0, 0};
    float f0, f1, f2, f3;
    int j = start;
    for (; j + 3 < end; j += 4) {
        int sA = adj[j + p], sB = adj[j + 2 + p];
        float wA = cn[sA], wB = cn[sB];
        uint2 vA = hp[sA * 32 + c];
        uint2 vB = hp[sB * 32 + c];
        bfu(vA.x, f0, f1); bfu(vA.y, f2, f3);
        A0[0] += f0 * wA; A0[1] += f1 * wA; A0[2] += f2 * wA; A0[3] += f3 * wA;
        bfu(vB.x, f0, f1); bfu(vB.y, f2, f3);
        A1[0] += f0 * wB; A1[1] += f1 * wB; A1[2] += f2 * wB; A1[3] += f3 * wB;
    }
    for (; j + 1 < end; j += 2) {
        int sA = adj[j + p];
        float wA = cn[sA];
        uint2 vA = hp[sA * 32 + c];
        bfu(vA.x, f0, f1); bfu(vA.y, f2, f3);
        A0[0] += f0 * wA; A0[1] += f1 * wA; A0[2] += f2 * wA; A0[3] += f3 * wA;
    }
    if (j < end && p == 0) {
        int sA = adj[j];
        float wA = cn[sA];
        uint2 vA = hp[sA * 32 + c];
        bfu(vA.x, f0, f1); bfu(vA.y, f2, f3);
        A0[0] += f0 * wA; A0[1] += f1 * wA; A0[2] += f2 * wA; A0[3] += f3 * wA;
    }
    float r0 = A0[0] + A1[0], r1 = A0[1] + A1[1], r2 = A0[2] + A1[2], r3 = A0[3] + A1[3];
    r0 += __shfl_xor(r0, 32, 64);
    r1 += __shfl_xor(r1, 32, 64);
    r2 += __shfl_xor(r2, 32, 64);
    r3 += __shfl_xor(r3, 32, 64);
    if (p == 0) {
        float4 o; o.x = r0; o.y = r1; o.z = r2; o.w = r3;
        ((float4*)acc1)[row * 32 + c] = o;
    }
}

// ------- gather 2: acc2[s] = sum_{d in adj_node[s]} hh2b[d] -----------------
__global__ __launch_bounds__(256) void k_gather2(const u16* __restrict__ hh2b,
                                                 const int* __restrict__ adj,
                                                 const int* __restrict__ ptr,
                                                 float* __restrict__ acc2) {
    int row = blockIdx.x * 4 + (threadIdx.x >> 6);
    int lane = threadIdx.x & 63;
    int p = lane >> 5, c = lane & 31;
    int start = (row == 0) ? 0 : ptr[row - 1];
    int end = ptr[row];
    const uint2* hp = (const uint2*)hh2b;
    float A0[4] = {0, 0, 0, 0}, A1[4] = {0, 0, 0, 0};
    float f0, f1, f2, f3;
    int j = start;
    for (; j + 3 < end; j += 4) {
        int dA = adj[j + p], dB = adj[j + 2 + p];
        uint2 vA = hp[dA * 32 + c];
        uint2 vB = hp[dB * 32 + c];
        bfu(vA.x, f0, f1); bfu(vA.y, f2, f3);
        A0[0] += f0; A0[1] += f1; A0[2] += f2; A0[3] += f3;
        bfu(vB.x, f0, f1); bfu(vB.y, f2, f3);
        A1[0] += f0; A1[1] += f1; A1[2] += f2; A1[3] += f3;
    }
    for (; j + 1 < end; j += 2) {
        int dA = adj[j + p];
        uint2 vA = hp[dA * 32 + c];
        bfu(vA.x, f0, f1); bfu(vA.y, f2, f3);
        A0[0] += f0; A0[1] += f1; A0[2] += f2; A0[3] += f3;
    }
    if (j < end && p == 0) {
        int dA = adj[j];
        uint2 vA = hp[dA * 32 + c];
        bfu(vA.x, f0, f1); bfu(vA.y, f2, f3);
        A0[0] += f0; A0[1] += f1; A0[2] += f2; A0[3] += f3;
    }
    float r0 = A0[0] + A1[0], r1 = A0[1] + A1[1], r2 = A0[2] + A1[2], r3 = A0[3] + A1[3];
    r0 += __shfl_xor(r0, 32, 64);
    r1 += __shfl_xor(r1, 32, 64);
    r2 += __shfl_xor(r2, 32, 64);
    r3 += __shfl_xor(r3, 32, 64);
    if (p == 0) {
        float4 o; o.x = r0; o.y = r1; o.z = r2; o.w = r3;
        ((float4*)acc2)[row * 32 + c] = o;
    }
}

// ------- GEMM1 (MFMA): hh2b = bf16(((acc1*ch) @ W1 + b1) * ch) --------------
__global__ __launch_bounds__(256) void k_gemm1(const float* __restrict__ a, const float* __restrict__ ch,
                                               const u16* __restrict__ W1t,
                                               const float* __restrict__ b1,
                                               u16* __restrict__ hh2b) {
    __shared__ u16 sA[64 * LDW];
    __shared__ u16 sW[128 * LDW];
    int tid = threadIdx.x;
    int r0 = blockIdx.x * 64;
    for (int i = tid; i < 64 * 32; i += 256) {
        int r = i >> 5, c4 = i & 31;
        int row = r0 + r; if (row > N_HYPER - 1) row = N_HYPER - 1;
        float4 v = *(const float4*)(a + row * 128 + c4 * 4);
        float cw = ch[row];
        u16* p = &sA[r * LDW + c4 * 4];
        p[0] = f2bf(v.x * cw); p[1] = f2bf(v.y * cw);
        p[2] = f2bf(v.z * cw); p[3] = f2bf(v.w * cw);
    }
    for (int i = tid; i < 128 * 16; i += 256) {
        int n = i >> 4, c = i & 15;
        *(uint4*)&sW[n * LDW + c * 8] = *(const uint4*)(W1t + n * 128 + c * 8);
    }
    __syncthreads();
    int w = tid >> 6, l15 = tid & 15, quad = (tid & 63) >> 4;
    f32x4 zero = {0.f, 0.f, 0.f, 0.f};
    f32x4 acc[8];
#pragma unroll
    for (int nt = 0; nt < 8; ++nt) acc[nt] = zero;
    int arow = w * 16 + l15;
#pragma unroll
    for (int kt = 0; kt < 4; ++kt) {
        bf16x8 af = *(bf16x8*)&sA[arow * LDW + kt * 32 + quad * 8];
#pragma unroll
        for (int nt = 0; nt < 8; ++nt) {
            bf16x8 bfv = *(bf16x8*)&sW[(nt * 16 + l15) * LDW + kt * 32 + quad * 8];
            acc[nt] = mfma16(af, bfv, acc[nt]);
        }
    }
#pragma unroll
    for (int r = 0; r < 4; ++r) {
        int row = r0 + w * 16 + quad * 4 + r;
        if (row < N_HYPER) {
            float cw = ch[row];
#pragma unroll
            for (int nt = 0; nt < 8; ++nt) {
                int n = nt * 16 + l15;
                hh2b[row * 128 + n] = f2bf((acc[nt][r] + b1[n]) * cw);
            }
        }
    }
}

// --- GEMM2 + residual + LN1 (MFMA, in-place): a := LN(h + (a*cn)@W2 + b2) ---
__global__ __launch_bounds__(256) void k_gemm2_ln(float* a, const float* __restrict__ cn,
                                                  const u16* __restrict__ W2t,
                                                  const float* __restrict__ b2,
                                                  const float* __restrict__ h,
                                                  const float* __restrict__ gamma1,
                                                  const float* __restrict__ beta1) {
    __shared__ u16 sA[64 * LDW];
    __shared__ u16 sW[128 * LDW];
    int tid = threadIdx.x;
    int r0 = blockIdx.x * 64;
    for (int i = tid; i < 64 * 32; i += 256) {
        int r = i >> 5, c4 = i & 31;
        int row = r0 + r; if (row > N_NODES - 1) row = N_NODES - 1;
        float4 v = *(const float4*)(a + row * 128 + c4 * 4);
        float cw = cn[row];
        u16* p = &sA[r * LDW + c4 * 4];
        p[0] = f2bf(v.x * cw); p[1] = f2bf(v.y * cw);
        p[2] = f2bf(v.z * cw); p[3] = f2bf(v.w * cw);
    }
    for (int i = tid; i < 128 * 16; i += 256) {
        int n = i >> 4, c = i & 15;
        *(uint4*)&sW[n * LDW + c * 8] = *(const uint4*)(W2t + n * 128 + c * 8);
    }
    __syncthreads();
    int w = tid >> 6, l15 = tid & 15, quad = (tid & 63) >> 4;
    f32x4 zero = {0.f, 0.f, 0.f, 0.f};
    f32x4 acc[8];
#pragma unroll
    for (int nt = 0; nt < 8; ++nt) acc[nt] = zero;
    int arow = w * 16 + l15;
#pragma unroll
    for (int kt = 0; kt < 4; ++kt) {
        bf16x8 af = *(bf16x8*)&sA[arow * LDW + kt * 32 + quad * 8];
#pragma unroll
        for (int nt = 0; nt < 8; ++nt) {
            bf16x8 bfv = *(bf16x8*)&sW[(nt * 16 + l15) * LDW + kt * 32 + quad * 8];
            acc[nt] = mfma16(af, bfv, acc[nt]);
        }
    }
    float s1[4] = {0, 0, 0, 0}, s2[4] = {0, 0, 0, 0};
#pragma unroll
    for (int r = 0; r < 4; ++r) {
        int row = r0 + w * 16 + quad * 4 + r;
        int rc = row > N_NODES - 1 ? N_NODES - 1 : row;
#pragma unroll
        for (int nt = 0; nt < 8; ++nt) {
            int n = nt * 16 + l15;
            float t = acc[nt][r] + b2[n] + h[rc * 128 + n];
            acc[nt][r] = t;
            s1[r] += t; s2[r] += t * t;
        }
    }
#pragma unroll
    for (int off = 1; off < 16; off <<= 1) {
#pragma unroll
        for (int r = 0; r < 4; ++r) {
            s1[r] += __shfl_xor(s1[r], off, 64);
            s2[r] += __shfl_xor(s2[r], off, 64);
        }
    }
#pragma unroll
    for (int r = 0; r < 4; ++r) {
        int row = r0 + w * 16 + quad * 4 + r;
        if (row < N_NODES) {
            float mu = s1[r] * (1.f / 128.f);
            float var = s2[r] * (1.f / 128.f) - mu * mu;
            float rs = rsqrtf(var + 1e-5f);
#pragma unroll
            for (int nt = 0; nt < 8; ++nt) {
                int n = nt * 16 + l15;
                a[row * 128 + n] = (acc[nt][r] - mu) * rs * gamma1[n] + beta1[n];
            }
        }
    }
}

// ------- FFN + residual + LN2 (MFMA): out = LN(h1 + relu(h1@W3+b3)@W4+b4) ---
__global__ __launch_bounds__(256) void k_ffn_ln(const float* __restrict__ h1,
                                                const u16* __restrict__ W3t,
                                                const float* __restrict__ b3,
                                                const u16* __restrict__ W4t,
                                                const float* __restrict__ b4,
                                                const float* __restrict__ gamma2,
                                                const float* __restrict__ beta2,
                                                float* __restrict__ out) {
    __shared__ u16 sA[64 * LDW];
    __shared__ u16 sW[128 * LDW];
    __shared__ u16 sY[64 * LDW];
    int tid = threadIdx.x;
    int r0 = blockIdx.x * 64;
    for (int i = tid; i < 64 * 32; i += 256) {
        int r = i >> 5, c4 = i & 31;
        int row = r0 + r; if (row > N_NODES - 1) row = N_NODES - 1;
        float4 v = *(const float4*)(h1 + row * 128 + c4 * 4);
        u16* p = &sA[r * LDW + c4 * 4];
        p[0] = f2bf(v.x); p[1] = f2bf(v.y); p[2] = f2bf(v.z); p[3] = f2bf(v.w);
    }
    int w = tid >> 6, l15 = tid & 15, quad = (tid & 63) >> 4;
    int arow = w * 16 + l15;
    f32x4 zero = {0.f, 0.f, 0.f, 0.f};
    f32x4 acc[8];
#pragma unroll
    for (int nt = 0; nt < 8; ++nt) acc[nt] = zero;

    for (int nc = 0; nc < 4; ++nc) {
        __syncthreads();
        for (int i = tid; i < 128 * 16; i += 256) {
            int n = i >> 4, c = i & 15;
            *(uint4*)&sW[n * LDW + c * 8] = *(const uint4*)(W3t + (nc * 128 + n) * 128 + c * 8);
        }
        __syncthreads();
        f32x4 y[8];
#pragma unroll
        for (int nt = 0; nt < 8; ++nt) y[nt] = zero;
#pragma unroll
        for (int kt = 0; kt < 4; ++kt) {
            bf16x8 af = *(bf16x8*)&sA[arow * LDW + kt * 32 + quad * 8];
#pragma unroll
            for (int nt = 0; nt < 8; ++nt) {
                bf16x8 bfv = *(bf16x8*)&sW[(nt * 16 + l15) * LDW + kt * 32 + quad * 8];
                y[nt] = mfma16(af, bfv, y[nt]);
            }
        }
#pragma unroll
        for (int r = 0; r < 4; ++r) {
            int yrow = w * 16 + quad * 4 + r;
#pragma unroll
            for (int nt = 0; nt < 8; ++nt) {
                int n = nt * 16 + l15;
                float vv = y[nt][r] + b3[nc * 128 + n];
                sY[yrow * LDW + n] = f2bf(vv > 0.f ? vv : 0.f);
            }
        }
        __syncthreads();
        for (int i = tid; i < 128 * 16; i += 256) {
            int n = i >> 4, c = i & 15;
            *(uint4*)&sW[n * LDW + c * 8] = *(const uint4*)(W4t + n * 512 + nc * 128 + c * 8);
        }
        __syncthreads();
#pragma unroll
        for (int kt = 0; kt < 4; ++kt) {
            bf16x8 af = *(bf16x8*)&sY[arow * LDW + kt * 32 + quad * 8];
#pragma unroll
            for (int nt = 0; nt < 8; ++nt) {
                bf16x8 bfv = *(bf16x8*)&sW[(nt * 16 + l15) * LDW + kt * 32 + quad * 8];
                acc[nt] = mfma16(af, bfv, acc[nt]);
            }
        }
    }
    float s1[4] = {0, 0, 0, 0}, s2[4] = {0, 0, 0, 0};
#pragma unroll
    for (int r = 0; r < 4; ++r) {
        int row = r0 + w * 16 + quad * 4 + r;
        int rc = row > N_NODES - 1 ? N_NODES - 1 : row;
#pragma unroll
        for (int nt = 0; nt < 8; ++nt) {
            int n = nt * 16 + l15;
            float t = acc[nt][r] + b4[n] + h1[rc * 128 + n];
            acc[nt][r] = t;
            s1[r] += t; s2[r] += t * t;
        }
    }
#pragma unroll
    for (int off = 1; off < 16; off <<= 1) {
#pragma unroll
        for (int r = 0; r < 4; ++r) {
            s1[r] += __shfl_xor(s1[r], off, 64);
            s2[r] += __shfl_xor(s2[r], off, 64);
        }
    }
#pragma unroll
    for (int r = 0; r < 4; ++r) {
        int row = r0 + w * 16 + quad * 4 + r;
        if (row < N_NODES) {
            float mu = s1[r] * (1.f / 128.f);
            float var = s2[r] * (1.f / 128.f) - mu * mu;
            float rs = rsqrtf(var + 1e-5f);
#pragma unroll
            for (int nt = 0; nt < 8; ++nt) {
                int n = nt * 16 + l15;
                out[row * 128 + n] = (acc[nt][r] - mu) * rs * gamma2[n] + beta2[n];
            }
        }
    }
}

extern "C" void kernel_launch(void* const* d_in, const int* in_sizes, int n_in,
                              void* d_out, int out_size, void* d_ws, size_t ws_size,
                              hipStream_t stream) {
    const float* h      = (const float*)d_in[0];
    const int*   src    = (const int*)d_in[1];
    const int*   dst    = (const int*)d_in[2];
    const float* W1     = (const float*)d_in[3];
    const float* b1     = (const float*)d_in[4];
    const float* W2     = (const float*)d_in[5];
    const float* b2     = (const float*)d_in[6];
    const float* W3     = (const float*)d_in[7];
    const float* b3     = (const float*)d_in[8];
    const float* W4     = (const float*)d_in[9];
    const float* b4     = (const float*)d_in[10];
    const float* gamma1 = (const float*)d_in[11];
    const float* beta1  = (const float*)d_in[12];
    const float* gamma2 = (const float*)d_in[13];
    const float* beta2  = (const float*)d_in[14];
    float* out = (float*)d_out;

    // ws layout (bytes), with dead-region aliasing:
    // ptr_node int[100000]     @ 0
    // ptr_he   int[20000]      @ 400000
    // adj_he   int[1.6M]       @ 480000    } hh2b bf16[20000*128] aliases adj_he after gather1
    // adj_node int[1.6M]       @ 6880000
    // cn       f32[100000]     @ 13280000
    // ch       f32[20000]      @ 13680000
    // acc1     f32[20000*128]  @ 13760000  } bs int[30] aliases acc1 during scan phase
    // acc2/h1  f32[100000*128] @ 24000000  } h_bf bf16[100000*128] aliases acc2 until gather2
    // W1t bf16[128*128]        @ 75200000
    // W2t bf16[128*128]        @ 75232768
    // W3t bf16[512*128]        @ 75265536
    // W4t bf16[128*512]        @ 75396608   (end 75527680)
    char* ws = (char*)d_ws;
    int*   ptr_node = (int*)(ws + 0);
    int*   ptr_he   = (int*)(ws + 400000);
    int*   adj_he   = (int*)(ws + 480000);
    int*   adj_node = (int*)(ws + 6880000);
    float* cn       = (float*)(ws + 13280000);
    float* ch       = (float*)(ws + 13680000);
    float* acc1     = (float*)(ws + 13760000);
    float* acc2     = (float*)(ws + 24000000);
    u16*   W1t      = (u16*)(ws + 75200000);
    u16*   W2t      = (u16*)(ws + 75232768);
    u16*   W3t      = (u16*)(ws + 75265536);
    u16*   W4t      = (u16*)(ws + 75396608);
    u16*   h_bf     = (u16*)(ws + 24000000);   // alias acc2 (dead until gather2)
    u16*   hh2b     = (u16*)(ws + 480000);     // alias adj_he (dead after gather1)
    int*   bs       = (int*)(ws + 13760000);   // alias acc1 (dead until gather1)

    hipMemsetAsync(d_ws, 0, 480000, stream);   // zero the two counter arrays only

    k_prep<<<12800, 256, 0, stream>>>(W1, W2, W3, W4, W1t, W2t, W3t, W4t, h, h_bf);
    k_hist<<<832, 256, 0, stream>>>(src, dst, ptr_node, ptr_he);
    k_scanA<<<30, 256, 0, stream>>>(ptr_node, ptr_he, bs);
    k_scanB<<<1, 64, 0, stream>>>(bs);
    k_scanC<<<30, 256, 0, stream>>>(ptr_node, ptr_he, cn, ch, bs);
    k_fill<<<832, 256, 0, stream>>>(src, dst, ptr_node, ptr_he, adj_node, adj_he);
    k_gather1<<<5000, 256, 0, stream>>>(h_bf, adj_he, ptr_he, cn, acc1);
    k_gemm1<<<313, 256, 0, stream>>>(acc1, ch, W1t, b1, hh2b);
    k_gather2<<<25000, 256, 0, stream>>>(hh2b, adj_node, ptr_node, acc2);
    k_gemm2_ln<<<1563, 256, 0, stream>>>(acc2, cn, W2t, b2, h, gamma1, beta1);
    k_ffn_ln<<<1563, 256, 0, stream>>>(acc2, W3t, b3, W4t, b4, gamma2, beta2, out);
}